// Round 9
// baseline (9402.708 us; speedup 1.0000x reference)
//
#include <hip/hip_runtime.h>
#include <hip/hip_bf16.h>
#include <math.h>

// ---- dims ----
#define Bn    128
#define NGn   2048
#define TTn   256
#define DOn   176
#define NBLK  256
#define NTHR  1024
#define HPAR  65536          // 512*128 uints per parity (k-major packed h)
#define NPAR  24576          // 192*128 uints per parity (k-major packed note)
#define PLGPOD 98304         // 32*16*192 floats per pod (partial logits)

typedef unsigned int uint;
using f32x4 = __attribute__((ext_vector_type(4))) float;
using s16x8 = __attribute__((ext_vector_type(8))) short;
union FR { uint u[4]; s16x8 s; };

struct KA {
  const float *z,*Wz,*bz,*cU1,*cb1,*cW2,*cU2,*cb2,*Wcd,*bcd;
  const float *dW1,*dU1,*db1,*dW2,*dU2,*db2,*Wp,*bp;
  float *zT,*sT,*ggate,*h1cT,*ceT,*sdT,*beffP,*db1P,*db2P,*WEp,*plg,*out;
  uint *WAh,*WAl,*WBh,*WBl,*ntpk,*h1pk,*h2pk,*dh1pk,*dh2pk;
};

// ---- barrier state ----
__device__ unsigned g_cnt_l1[16 * 32];
__device__ unsigned g_cnt;
__device__ unsigned g_gen;
__device__ unsigned pod_leaf[8 * 4 * 32];
__device__ unsigned pod_root[8 * 32];
__device__ unsigned pod_gen[8 * 32];

__device__ __forceinline__ float sigm(float x) { return 1.0f / (1.0f + __expf(-x)); }

__device__ __forceinline__ float aloadF(const float* p) {
  return __hip_atomic_load(p, __ATOMIC_RELAXED, __HIP_MEMORY_SCOPE_AGENT);
}
__device__ __forceinline__ void astoreF(float* p, float v) {
  __hip_atomic_store(p, v, __ATOMIC_RELAXED, __HIP_MEMORY_SCOPE_AGENT);
}
__device__ __forceinline__ uint aloadU(const uint* p) {
  return __hip_atomic_load(p, __ATOMIC_RELAXED, __HIP_MEMORY_SCOPE_AGENT);
}
__device__ __forceinline__ void astoreU(uint* p, uint v) {
  __hip_atomic_store(p, v, __ATOMIC_RELAXED, __HIP_MEMORY_SCOPE_AGENT);
}

// split v = hi + lo (both bf16, RNE)
__device__ __forceinline__ void split2(float v, unsigned short& h, unsigned short& l) {
  __hip_bfloat16 bh = __float2bfloat16(v);
  float hf = __bfloat162float(bh);
  __hip_bfloat16 bl = __float2bfloat16(v - hf);
  h = *(unsigned short*)&bh; l = *(unsigned short*)&bl;
}
__device__ __forceinline__ uint packsplit(float v) {
  unsigned short h, l; split2(v, h, l);
  return (uint)h | ((uint)l << 16);
}

// global barrier (preamble only)
__device__ __forceinline__ void gbar() {
  __syncthreads();
  if (threadIdx.x == 0) {
    asm volatile("s_waitcnt vmcnt(0)" ::: "memory");
    unsigned g0 = __hip_atomic_load(&g_gen, __ATOMIC_RELAXED, __HIP_MEMORY_SCOPE_AGENT);
    unsigned p1 = __hip_atomic_fetch_add(&g_cnt_l1[(blockIdx.x >> 4) * 32], 1u,
                                         __ATOMIC_RELAXED, __HIP_MEMORY_SCOPE_AGENT);
    if (p1 == 15u) {
      unsigned p2 = __hip_atomic_fetch_add(&g_cnt, 1u, __ATOMIC_RELAXED, __HIP_MEMORY_SCOPE_AGENT);
      if (p2 == 15u) {
        #pragma unroll
        for (int i = 0; i < 16; i++)
          __hip_atomic_store(&g_cnt_l1[i * 32], 0u, __ATOMIC_RELAXED, __HIP_MEMORY_SCOPE_AGENT);
        __hip_atomic_store(&g_cnt, 0u, __ATOMIC_RELAXED, __HIP_MEMORY_SCOPE_AGENT);
        asm volatile("s_waitcnt vmcnt(0)" ::: "memory");
        __hip_atomic_fetch_add(&g_gen, 1u, __ATOMIC_RELAXED, __HIP_MEMORY_SCOPE_AGENT);
      }
    }
    while (__hip_atomic_load(&g_gen, __ATOMIC_RELAXED, __HIP_MEMORY_SCOPE_AGENT) == g0)
      __builtin_amdgcn_s_sleep(1);
  }
  __syncthreads();
}

// pod barrier: 32 blocks = 4 leaves x 8 (round-7 proven)
__device__ __forceinline__ void pbar(int pod, int j) {
  __syncthreads();
  if (threadIdx.x == 0) {
    asm volatile("s_waitcnt vmcnt(0)" ::: "memory");
    unsigned* gen = &pod_gen[pod * 32];
    unsigned g0 = __hip_atomic_load(gen, __ATOMIC_RELAXED, __HIP_MEMORY_SCOPE_AGENT);
    unsigned p = __hip_atomic_fetch_add(&pod_leaf[(pod * 4 + (j >> 3)) * 32], 1u,
                                        __ATOMIC_RELAXED, __HIP_MEMORY_SCOPE_AGENT);
    if (p == 7u) {
      unsigned q = __hip_atomic_fetch_add(&pod_root[pod * 32], 1u,
                                          __ATOMIC_RELAXED, __HIP_MEMORY_SCOPE_AGENT);
      if (q == 3u) {
        #pragma unroll
        for (int l = 0; l < 4; l++)
          __hip_atomic_store(&pod_leaf[(pod * 4 + l) * 32], 0u, __ATOMIC_RELAXED, __HIP_MEMORY_SCOPE_AGENT);
        __hip_atomic_store(&pod_root[pod * 32], 0u, __ATOMIC_RELAXED, __HIP_MEMORY_SCOPE_AGENT);
        asm volatile("s_waitcnt vmcnt(0)" ::: "memory");
        __hip_atomic_fetch_add(gen, 1u, __ATOMIC_RELAXED, __HIP_MEMORY_SCOPE_AGENT);
      }
    }
    while (__hip_atomic_load(gen, __ATOMIC_RELAXED, __HIP_MEMORY_SCOPE_AGENT) == g0) { }
  }
  __syncthreads();
}

// ---------------- preamble f32 helpers (rounds 4-7 proven) ----------------
__device__ __forceinline__ void stageN(float* __restrict__ xs, const float* __restrict__ X,
                                       int nrows, int b0, int tid) {
  for (int i = tid; i < nrows * 16; i += NTHR)
    xs[i] = aloadF(X + (size_t)(i >> 4) * Bn + b0 + (i & 15));
}

template<int KC>
__device__ __forceinline__ void gemm16(const float* __restrict__ Wb, int colbase,
                                       int kq, int cg, int bg,
                                       const float* __restrict__ xsrc, float acc[16]) {
  const float* wp = Wb + (size_t)(kq * KC) * NGn + colbase + cg * 4;
  const float* xp = xsrc + (kq * KC) * 16 + bg * 4;
  #pragma unroll 2
  for (int kk = 0; kk < KC; kk++) {
    const float4 w4 = *(const float4*)(wp);
    const float4 x4 = *(const float4*)(xp);
    acc[0]  = fmaf(w4.x, x4.x, acc[0]);  acc[1]  = fmaf(w4.x, x4.y, acc[1]);
    acc[2]  = fmaf(w4.x, x4.z, acc[2]);  acc[3]  = fmaf(w4.x, x4.w, acc[3]);
    acc[4]  = fmaf(w4.y, x4.x, acc[4]);  acc[5]  = fmaf(w4.y, x4.y, acc[5]);
    acc[6]  = fmaf(w4.y, x4.z, acc[6]);  acc[7]  = fmaf(w4.y, x4.w, acc[7]);
    acc[8]  = fmaf(w4.z, x4.x, acc[8]);  acc[9]  = fmaf(w4.z, x4.y, acc[9]);
    acc[10] = fmaf(w4.z, x4.z, acc[10]); acc[11] = fmaf(w4.z, x4.w, acc[11]);
    acc[12] = fmaf(w4.w, x4.x, acc[12]); acc[13] = fmaf(w4.w, x4.y, acc[13]);
    acc[14] = fmaf(w4.w, x4.z, acc[14]); acc[15] = fmaf(w4.w, x4.w, acc[15]);
    wp += NGn; xp += 16;
  }
}

__device__ __forceinline__ void pstore(float* __restrict__ part, int kq, int cg, int bg,
                                       const float acc[16]) {
  #pragma unroll
  for (int c = 0; c < 4; c++) {
    float* p = part + (size_t)(kq * 64 + cg * 4 + c) * 17 + bg * 4;
    *(float4*)p = make_float4(acc[c*4], acc[c*4+1], acc[c*4+2], acc[c*4+3]);
  }
}

template<int MODE>
__device__ __forceinline__ void epi_plain(const float* bias, float* out,
                                          int colbase, int b0, int tid,
                                          const float* __restrict__ part) {
  int cl = tid >> 4, bl = tid & 15;
  float s = 0.0f;
  #pragma unroll
  for (int w = 0; w < 8; w++) s += part[(w * 64 + cl) * 17 + bl];
  if (bias) s += bias[colbase + cl];
  if (MODE == 0) s = tanhf(s);
  astoreF(out + (size_t)(colbase + cl) * Bn + b0 + bl, s);
}

__device__ __forceinline__ void cond_nl(const float* gb, const float* cbias,
                                        const float* cin, float* hout, int bid, int tid) {
  int i = bid * NTHR + tid;
  if (i < 512 * Bn) {
    int hid = i >> 7, b = i & 127;
    float gi = aloadF(gb + (size_t)hid * Bn + b)            + cbias[hid];
    float gf = aloadF(gb + (size_t)(512 + hid) * Bn + b)    + cbias[512 + hid];
    float gg = aloadF(gb + (size_t)(1024 + hid) * Bn + b)   + cbias[1024 + hid];
    float go = aloadF(gb + (size_t)(1536 + hid) * Bn + b)   + cbias[1536 + hid];
    float cprev = aloadF(cin + (size_t)hid * Bn + b);
    float c = sigm(gf) * cprev + sigm(gi) * tanhf(gg);
    astoreF(hout + (size_t)hid * Bn + b, sigm(go) * tanhf(c));
  }
}

// ---------------- main-loop MFMA machinery ----------------
// frag maps (rounds 5-7 verified): A(x): m=lane&15, k=(lane>>4)*8+e.
// B(w): n=lane&15, k=(lane>>4)*8+e. D: n=lane&15, m=(lane>>4)*4+reg.
// LDS x tiles: stride 17 uints/row, 16 valid batch cols (= pod width) -> no junk lanes.
__device__ __forceinline__ void ldxL17(const uint* __restrict__ p, FR& xh, FR& xl) {
  uint w[8];
  #pragma unroll
  for (int e = 0; e < 8; e++) w[e] = p[e * 17];
  xh.u[0] = (w[0] & 0xffffu) | (w[1] << 16); xl.u[0] = (w[0] >> 16) | (w[1] & 0xffff0000u);
  xh.u[1] = (w[2] & 0xffffu) | (w[3] << 16); xl.u[1] = (w[2] >> 16) | (w[3] & 0xffff0000u);
  xh.u[2] = (w[4] & 0xffffu) | (w[5] << 16); xl.u[2] = (w[4] >> 16) | (w[5] & 0xffff0000u);
  xh.u[3] = (w[6] & 0xffffu) | (w[7] << 16); xl.u[3] = (w[6] >> 16) | (w[7] & 0xffff0000u);
}

struct MC {
  const uint *WAh,*WAl,*WBh,*WBl,*dh1pk,*dh2pk;
  uint *ntpk,*h1pk,*h2pk;
  const float *beffP,*db2P,*Wp,*bp;
  float *plg;                     // pod-offset partial logits [j*16+bl][192]
  float *out;
  uint *SBu,*NTu;                 // LDS stage: SB 1024x17, NT 192x17
  float *plog,*gbuf,*cst,*h2s;    // LDS
  int j, b0;
};

#define MFMA3(ACC, XH, XL, WH, WL)                                            \
  ACC = __builtin_amdgcn_mfma_f32_16x16x32_bf16(XH.s, WH.s, ACC, 0, 0, 0);    \
  ACC = __builtin_amdgcn_mfma_f32_16x16x32_bf16(XL.s, WH.s, ACC, 0, 0, 0);    \
  ACC = __builtin_amdgcn_mfma_f32_16x16x32_bf16(XH.s, WL.s, ACC, 0, 0, 0);

// stage 512 k-rows x 16 batches into SBu at row offset r0 (batched coalesced loads)
__device__ __forceinline__ void stageSB16(uint* __restrict__ SBu, int r0,
                                          const uint* __restrict__ src, int b0, int tid) {
  #pragma unroll
  for (int rep = 0; rep < 8; rep++) {
    int idx = tid + rep * NTHR;              // 0..8191
    int k = idx >> 4, bl = idx & 15;
    SBu[(r0 + k) * 17 + bl] = aloadU(src + k * 128 + b0 + bl);
  }
}
// stage 192 note rows x 16 batches
__device__ __forceinline__ void stageNT16(uint* __restrict__ NTu,
                                          const uint* __restrict__ src, int b0, int tid) {
  #pragma unroll
  for (int rep = 0; rep < 3; rep++) {
    int idx = tid + rep * NTHR;              // 0..3071
    int k = idx >> 4, bl = idx & 15;
    NTu[k * 17 + bl] = aloadU(src + k * 128 + b0 + bl);
  }
}

// phase A: decoder L1 (K=704: note ks 0..5 from NT, h1(t-1) ks 6..21 from SB[0..512))
// SB[0..512) holds h1(t-1) left by phaseB(t-1); at reset it is overwritten with dh1.
__device__ __forceinline__ void phaseA(const MC& c, int t) {
  const int tid = threadIdx.x, wid = tid >> 6, lane = tid & 63;
  const int m = lane & 15, kh = lane >> 4;
  const int nt = wid & 3, ksq = wid >> 2;
  const int par = t & 1; const bool rst = (t & 15) == 0;
  stageNT16(c.NTu, c.ntpk + par * NPAR, c.b0, tid);
  stageSB16(c.SBu, 512, rst ? c.dh2pk : (c.h2pk + (par ^ 1) * HPAR), c.b0, tid);  // for phase B
  if (rst) stageSB16(c.SBu, 0, c.dh1pk, c.b0, tid);
  __syncthreads();
  const int s0 = (ksq == 0) ? 0 : (ksq == 1) ? 6 : (ksq == 2) ? 12 : 17;
  const int s1 = (ksq == 0) ? 6 : (ksq == 1) ? 12 : (ksq == 2) ? 17 : 22;
  f32x4 acc = {0.f,0.f,0.f,0.f};
  for (int ks = s0; ks < s1; ks++) {
    const uint* xp = (ks < 6) ? (c.NTu + (ks * 32 + kh * 8) * 17 + m)
                              : (c.SBu + ((ks - 6) * 32 + kh * 8) * 17 + m);
    FR xh, xl; ldxL17(xp, xh, xl);
    FR wh, wl;
    *(uint4*)wh.u = *(const uint4*)(c.WAh + (size_t)c.j * 22528 + (ks * 4 + nt) * 256 + lane * 4);
    *(uint4*)wl.u = *(const uint4*)(c.WAl + (size_t)c.j * 22528 + (ks * 4 + nt) * 256 + lane * 4);
    MFMA3(acc, xh, xl, wh, wl)
  }
  #pragma unroll
  for (int r = 0; r < 4; r++) c.plog[((ksq * 4 + nt) * 4 + r) * 64 + lane] = acc[r];
  __syncthreads();
  {
    int cl = tid >> 4, bl = tid & 15;
    float s = 0.f;
    #pragma unroll
    for (int k2 = 0; k2 < 4; k2++)
      s += c.plog[((k2 * 4 + (cl >> 4)) * 4 + (bl & 3)) * 64 + (bl >> 2) * 16 + (cl & 15)];
    c.gbuf[cl * 16 + bl] = s + c.beffP[(size_t)(c.j * 64 + cl) * Bn + c.b0 + bl];
  }
  __syncthreads();
  if (tid < 256) {
    int h = tid >> 4, bl = tid & 15;
    float gi = c.gbuf[(h*4+0)*16+bl], gf = c.gbuf[(h*4+1)*16+bl];
    float gg = c.gbuf[(h*4+2)*16+bl], go = c.gbuf[(h*4+3)*16+bl];
    float cp = rst ? c.cst[512 + tid] : c.cst[tid];
    float cc = sigm(gf) * cp + sigm(gi) * tanhf(gg);
    c.cst[tid] = cc;
    astoreU(c.h1pk + par * HPAR + (size_t)(c.j * 16 + h) * 128 + c.b0 + bl,
            packsplit(sigm(go) * tanhf(cc)));
  }
}

// phase B: decoder L2 (K=1024: h1(t) rows 0..511 staged here, h2(t-1)/dh2 rows 512..1023
// staged in phase A) + per-block partial projection logits
__device__ __forceinline__ void phaseB(const MC& c, int t) {
  const int tid = threadIdx.x, wid = tid >> 6, lane = tid & 63;
  const int m = lane & 15, kh = lane >> 4;
  const int nt = wid & 3, ksq = wid >> 2;
  const int par = t & 1; const bool rst = (t & 15) == 0;
  stageSB16(c.SBu, 0, c.h1pk + par * HPAR, c.b0, tid);   // h1(t) from whole pod
  __syncthreads();
  f32x4 acc = {0.f,0.f,0.f,0.f};
  #pragma unroll
  for (int kk = 0; kk < 8; kk++) {
    const int ks = ksq * 8 + kk;
    const uint* xp = c.SBu + (ks * 32 + kh * 8) * 17 + m;   // rows 0..1023 (512+ = h2)
    FR xh, xl; ldxL17(xp, xh, xl);
    FR wh, wl;
    *(uint4*)wh.u = *(const uint4*)(c.WBh + (size_t)c.j * 32768 + (ks * 4 + nt) * 256 + lane * 4);
    *(uint4*)wl.u = *(const uint4*)(c.WBl + (size_t)c.j * 32768 + (ks * 4 + nt) * 256 + lane * 4);
    MFMA3(acc, xh, xl, wh, wl)
  }
  #pragma unroll
  for (int r = 0; r < 4; r++) c.plog[((ksq * 4 + nt) * 4 + r) * 64 + lane] = acc[r];
  __syncthreads();
  {
    int cl = tid >> 4, bl = tid & 15;
    float s = 0.f;
    #pragma unroll
    for (int k2 = 0; k2 < 4; k2++)
      s += c.plog[((k2 * 4 + (cl >> 4)) * 4 + (bl & 3)) * 64 + (bl >> 2) * 16 + (cl & 15)];
    c.gbuf[cl * 16 + bl] = s + c.db2P[c.j * 64 + cl];
  }
  __syncthreads();
  if (tid < 256) {
    int h = tid >> 4, bl = tid & 15;
    float gi = c.gbuf[(h*4+0)*16+bl], gf = c.gbuf[(h*4+1)*16+bl];
    float gg = c.gbuf[(h*4+2)*16+bl], go = c.gbuf[(h*4+3)*16+bl];
    float cp = rst ? c.cst[768 + tid] : c.cst[256 + tid];
    float cc = sigm(gf) * cp + sigm(gi) * tanhf(gg);
    c.cst[256 + tid] = cc;
    float h2v = sigm(go) * tanhf(cc);
    c.h2s[h * 16 + bl] = h2v;
    astoreU(c.h2pk + par * HPAR + (size_t)(c.j * 16 + h) * 128 + c.b0 + bl, packsplit(h2v));
  }
  __syncthreads();
  // partial projection logits over this block's 16-hid slice (f32 VALU)
  const int o = tid & 255, q = tid >> 8;
  if (o < DOn) {
    float wv[16];
    #pragma unroll
    for (int h = 0; h < 16; h++) wv[h] = c.Wp[(size_t)(c.j * 16 + h) * DOn + o];
    #pragma unroll
    for (int rep = 0; rep < 4; rep++) {
      const int bl = q * 4 + rep;
      float s = 0.f;
      #pragma unroll
      for (int h = 0; h < 16; h++) s = fmaf(c.h2s[h * 16 + bl], wv[h], s);
      astoreF(c.plg + (size_t)(c.j * 16 + bl) * 192 + o, s);
    }
  }
}

// phase C: owners (j<16) sum 32 partials for batch b0+j, softmax, write note + out
__device__ __forceinline__ void phaseC(const MC& c, int t) {
  if (c.j >= 16) return;
  const int tid = threadIdx.x;
  const int par = t & 1;
  const int b = c.b0 + c.j;
  const int o = tid & 255, q = tid >> 8;
  float s = 0.f;
  if (o < DOn) {
    #pragma unroll
    for (int jj = 0; jj < 8; jj++)
      s += aloadF(c.plg + (size_t)((q * 8 + jj) * 16 + c.j) * 192 + o);
  }
  c.gbuf[q * 256 + o] = s;
  __syncthreads();
  float lg = -1e30f;
  if (tid < 256) {
    float sv = c.gbuf[tid] + c.gbuf[256 + tid] + c.gbuf[512 + tid] + c.gbuf[768 + tid];
    lg = (tid < DOn) ? sv + c.bp[tid] : -1e30f;
    c.plog[tid] = lg;
  }
  __syncthreads();
  for (int st = 128; st > 0; st >>= 1) {
    if (tid < st) c.plog[tid] = fmaxf(c.plog[tid], c.plog[tid + st]);
    __syncthreads();
  }
  const float mx = c.plog[0];
  float e = 0.f;
  if (tid < 256) {
    e = (tid < DOn) ? __expf(lg - mx) : 0.f;
    c.plog[260 + tid] = e;
  }
  __syncthreads();
  for (int st = 128; st > 0; st >>= 1) {
    if (tid < st) c.plog[260 + tid] += c.plog[260 + tid + st];
    __syncthreads();
  }
  const float inv = 1.0f / c.plog[260];
  if (tid < DOn) {
    const float p = e * inv;
    astoreU(c.ntpk + (par ^ 1) * NPAR + tid * 128 + b, packsplit(p));
    c.out[((size_t)b * TTn + t) * DOn + tid] = p;
  }
}

// ---------------- kernel ----------------
__global__ void __launch_bounds__(NTHR, 1)
hd_kernel(KA A) {
  __shared__ float buf[27072];   // preamble: xs[16384]+part[8704]; main: SB/NT/plog/gbuf/cst/h2s
  float* xs = buf;
  float* part = buf + 16384;
  const int bid = blockIdx.x, tid = threadIdx.x;
  const int lane = tid & 63;
  const int kqP = tid >> 6, cgP = lane & 15, bgP = lane >> 4;   // preamble gemm (tid<512)
  const int rP = bid & 31, btP = bid >> 5;
  const int htP = (rP & 7) * 4 + (rP >> 3);
  const int colbaseP = htP * 64, b0P = btP * 16;

  // ---- P-1: z transpose, bias perms, WEp, WA pack, note zero ----
  {
    const int i0 = bid * NTHR + tid;                 // 0..262143
    if (i0 < 512 * Bn) { int zb = i0 >> 9, zk = i0 & 511; astoreF(A.zT + (size_t)zk * Bn + zb, A.z[i0]); }
    if (i0 < NGn) {
      int hid = i0 >> 2, g = i0 & 3, sc = g * 512 + hid;
      astoreF(A.db1P + i0, A.db1[sc]);
      astoreF(A.db2P + i0, A.db2[sc]);
    }
    if (i0 < NPAR) astoreU(A.ntpk + i0, 0u);                        // parity 0: all rows
    if (i0 < 2048) astoreU(A.ntpk + NPAR + 176 * 128 + i0, 0u);     // parity 1: pad rows
    for (int i = i0; i < 512 * NGn; i += NBLK * NTHR) {   // WEp[k][cp]
      int k = i >> 11, pc = i & 2047;
      int hid = pc >> 2, g = pc & 3;
      astoreF(A.WEp + i, A.dW1[(size_t)(176 + k) * NGn + g * 512 + hid]);
    }
    for (int i = i0; i < 720896; i += NBLK * NTHR) {      // WA frag planes
      int col = i & 2047, kp = i >> 11, k = kp * 2;
      float w0, w1;
      if (k < 176)      { w0 = A.dW1[(size_t)k * NGn + col];       w1 = A.dW1[(size_t)(k + 1) * NGn + col]; }
      else if (k < 192) { w0 = 0.f; w1 = 0.f; }
      else              { w0 = A.dU1[(size_t)(k - 192) * NGn + col]; w1 = A.dU1[(size_t)(k - 191) * NGn + col]; }
      unsigned short h0, l0, h1, l1; split2(w0, h0, l0); split2(w1, h1, l1);
      int g = col >> 9, hid = col & 511;
      int jj = hid >> 4, cl = (hid & 15) * 4 + g;
      int nt = cl >> 4, n = cl & 15;
      int ks = k >> 5, kr = k & 31, lh = kr >> 3, q = (kr >> 1) & 3;
      int idx = ((jj * 22 + ks) * 4 + nt) * 256 + (lh * 16 + n) * 4 + q;
      astoreU(A.WAh + idx, (uint)h0 | ((uint)h1 << 16));
      astoreU(A.WAl + idx, (uint)l0 | ((uint)l1 << 16));
    }
  }
  gbar();
  // ---- pre0: sT = tanh(z @ Wz + bz) ----
  {
    stageN(xs, A.zT, 512, b0P, tid); __syncthreads();
    if (tid < 512) {
      float acc[16] = {0,0,0,0,0,0,0,0,0,0,0,0,0,0,0,0};
      gemm16<64>(A.Wz, colbaseP, kqP, cgP, bgP, xs, acc);
      pstore(part, kqP, cgP, bgP, acc);
    }
    __syncthreads();
    epi_plain<0>(A.bz, A.sT, colbaseP, b0P, tid, part);
  }
  gbar();
  // ---- pre1: conductor L1 gates ----
  {
    stageN(xs, A.sT, 512, b0P, tid); __syncthreads();
    if (tid < 512) {
      float acc[16] = {0,0,0,0,0,0,0,0,0,0,0,0,0,0,0,0};
      gemm16<64>(A.cU1, colbaseP, kqP, cgP, bgP, xs, acc);
      pstore(part, kqP, cgP, bgP, acc);
    }
    __syncthreads();
    epi_plain<1>(nullptr, A.ggate, colbaseP, b0P, tid, part);
  }
  gbar();
  cond_nl(A.ggate, A.cb1, A.sT + (size_t)512 * Bn, A.h1cT, bid, tid);
  gbar();
  // ---- pre2: conductor L2 gates ----
  {
    stageN(xs, A.h1cT, 512, b0P, tid);
    stageN(xs + 8192, A.sT + (size_t)1024 * Bn, 512, b0P, tid);
    __syncthreads();
    if (tid < 512) {
      float acc[16] = {0,0,0,0,0,0,0,0,0,0,0,0,0,0,0,0};
      gemm16<64>(A.cW2, colbaseP, kqP, cgP, bgP, xs, acc);
      gemm16<64>(A.cU2, colbaseP, kqP, cgP, bgP, xs + 8192, acc);
      pstore(part, kqP, cgP, bgP, acc);
    }
    __syncthreads();
    epi_plain<1>(nullptr, A.ggate, colbaseP, b0P, tid, part);
  }
  gbar();
  cond_nl(A.ggate, A.cb2, A.sT + (size_t)1536 * Bn, A.ceT, bid, tid);
  gbar();
  // ---- pre3: sdT = tanh(ce @ Wcd + bcd); beffP = db1P + ce @ WEp ----
  {
    stageN(xs, A.ceT, 512, b0P, tid); __syncthreads();
    if (tid < 512) {
      float acc[16] = {0,0,0,0,0,0,0,0,0,0,0,0,0,0,0,0};
      gemm16<64>(A.Wcd, colbaseP, kqP, cgP, bgP, xs, acc);
      pstore(part, kqP, cgP, bgP, acc);
    }
    __syncthreads();
    epi_plain<0>(A.bcd, A.sdT, colbaseP, b0P, tid, part);
    __syncthreads();
    if (tid < 512) {
      float acc[16] = {0,0,0,0,0,0,0,0,0,0,0,0,0,0,0,0};
      gemm16<64>(A.WEp, colbaseP, kqP, cgP, bgP, xs, acc);
      pstore(part, kqP, cgP, bgP, acc);
    }
    __syncthreads();
    epi_plain<1>(A.db1P, A.beffP, colbaseP, b0P, tid, part);
  }
  gbar();
  // ---- P4: WB pack (overwrites WEp) + dh packs (k-major) ----
  {
    const int i0 = bid * NTHR + tid;
    for (int i = i0; i < 1048576; i += NBLK * NTHR) {
      int col = i & 2047, kp = i >> 11, k = kp * 2;
      float w0, w1;
      if (k < 512) { w0 = A.dW2[(size_t)k * NGn + col];         w1 = A.dW2[(size_t)(k + 1) * NGn + col]; }
      else         { w0 = A.dU2[(size_t)(k - 512) * NGn + col]; w1 = A.dU2[(size_t)(k - 511) * NGn + col]; }
      unsigned short h0, l0, h1, l1; split2(w0, h0, l0); split2(w1, h1, l1);
      int g = col >> 9, hid = col & 511;
      int jj = hid >> 4, cl = (hid & 15) * 4 + g;
      int nt = cl >> 4, n = cl & 15;
      int ks = k >> 5, kr = k & 31, lh = kr >> 3, q = (kr >> 1) & 3;
      int idx = ((jj * 32 + ks) * 4 + nt) * 256 + (lh * 16 + n) * 4 + q;
      astoreU(A.WBh + idx, (uint)h0 | ((uint)h1 << 16));
      astoreU(A.WBl + idx, (uint)l0 | ((uint)l1 << 16));
    }
    if (i0 < 512 * Bn) {
      int hid = i0 >> 7, b = i0 & 127;
      astoreU(A.dh1pk + hid * 128 + b, packsplit(aloadF(A.sdT + (size_t)hid * Bn + b)));
      astoreU(A.dh2pk + hid * 128 + b, packsplit(aloadF(A.sdT + (size_t)(1024 + hid) * Bn + b)));
    }
  }
  gbar();

  // ---- main loop ----
  MC c;
  c.WAh = A.WAh; c.WAl = A.WAl; c.WBh = A.WBh; c.WBl = A.WBl;
  c.dh1pk = A.dh1pk; c.dh2pk = A.dh2pk;
  c.ntpk = A.ntpk; c.h1pk = A.h1pk; c.h2pk = A.h2pk;
  c.beffP = A.beffP; c.db2P = A.db2P; c.Wp = A.Wp; c.bp = A.bp; c.out = A.out;
  c.SBu = (uint*)buf;            // 1024 x 17 = 17408
  c.NTu = (uint*)(buf + 17408);  // 192 x 17 = 3264
  c.plog = buf + 20672;          // 4096
  c.gbuf = buf + 24768;          // 1024
  c.cst  = buf + 25792;          // 1024
  c.h2s  = buf + 26816;          // 256
  c.j = bid & 31;
  const int pod = bid >> 5;
  c.b0 = pod * 16;
  c.plg = A.plg + (size_t)pod * PLGPOD;
  if (tid < 256) {
    int h = tid >> 4, bl = tid & 15;
    c.cst[512 + tid] = aloadF(A.sdT + (size_t)(512 + c.j * 16 + h) * Bn + c.b0 + bl);
    c.cst[768 + tid] = aloadF(A.sdT + (size_t)(1536 + c.j * 16 + h) * Bn + c.b0 + bl);
  }
  __syncthreads();

  for (int t = 0; t < TTn; t++) {
    phaseA(c, t);
    pbar(pod, c.j);
    phaseB(c, t);
    pbar(pod, c.j);
    phaseC(c, t);
    pbar(pod, c.j);
  }
}

extern "C" void kernel_launch(void* const* d_in, const int* in_sizes, int n_in,
                              void* d_out, int out_size, void* d_ws, size_t ws_size,
                              hipStream_t stream) {
  (void)in_sizes; (void)n_in; (void)out_size; (void)ws_size;
  KA a;
  a.z   = (const float*)d_in[0];
  a.Wz  = (const float*)d_in[3];  a.bz  = (const float*)d_in[4];
  // d_in[5] = cond_W1 unused (conductor input x0 == 0)
  a.cU1 = (const float*)d_in[6];  a.cb1 = (const float*)d_in[7];
  a.cW2 = (const float*)d_in[8];  a.cU2 = (const float*)d_in[9];  a.cb2 = (const float*)d_in[10];
  a.Wcd = (const float*)d_in[11]; a.bcd = (const float*)d_in[12];
  a.dW1 = (const float*)d_in[13]; a.dU1 = (const float*)d_in[14]; a.db1 = (const float*)d_in[15];
  a.dW2 = (const float*)d_in[16]; a.dU2 = (const float*)d_in[17]; a.db2 = (const float*)d_in[18];
  a.Wp  = (const float*)d_in[19]; a.bp  = (const float*)d_in[20];

  float* ws = (float*)d_ws;
  size_t off = 0;
  a.zT    = ws + off; off += (size_t)512  * Bn;
  a.sT    = ws + off; off += (size_t)NGn  * Bn;
  a.ggate = ws + off; off += (size_t)NGn  * Bn;
  a.h1cT  = ws + off; off += (size_t)512  * Bn;
  a.ceT   = ws + off; off += (size_t)512  * Bn;
  a.sdT   = ws + off; off += (size_t)NGn  * Bn;       // dh1|dc1|dh2|dc2
  a.beffP = ws + off; off += (size_t)NGn  * Bn;       // [cp][b]
  a.db1P  = ws + off; off += (size_t)NGn;
  a.db2P  = ws + off; off += (size_t)NGn;
  a.WEp   = ws + off; off += (size_t)512 * NGn;       // aliased by WBh in P4
  a.WBh   = (uint*)a.WEp;
  a.WBl   = (uint*)(ws + off); off += (size_t)1048576;
  a.WAh   = (uint*)(ws + off); off += (size_t)720896;
  a.WAl   = (uint*)(ws + off); off += (size_t)720896;
  a.ntpk  = (uint*)(ws + off); off += (size_t)2 * NPAR;
  a.h1pk  = (uint*)(ws + off); off += (size_t)2 * HPAR;
  a.h2pk  = (uint*)(ws + off); off += (size_t)2 * HPAR;
  a.dh1pk = (uint*)(ws + off); off += (size_t)HPAR;
  a.dh2pk = (uint*)(ws + off); off += (size_t)HPAR;
  a.plg   = ws + off; off += (size_t)8 * PLGPOD;
  a.out   = (float*)d_out;

  hd_kernel<<<dim3(NBLK), dim3(NTHR), 0, stream>>>(a);
}

// Round 10
// 7773.346 us; speedup vs baseline: 1.2096x; 1.2096x over previous
//
#include <hip/hip_runtime.h>
#include <hip/hip_bf16.h>
#include <math.h>

// ---- dims ----
#define Bn    128
#define NGn   2048
#define TTn   256
#define DOn   176
#define NBLK  256
#define NTHR  1024
#define HPAR  65536          // 512*128 uints per parity (k-major packed h)
#define ACC_PAR 24576        // ints per parity in accI (8 pods x 16 b x 192)

typedef unsigned int uint;
using f32x4 = __attribute__((ext_vector_type(4))) float;
using s16x8 = __attribute__((ext_vector_type(8))) short;
union FR { uint u[4]; s16x8 s; };

struct KA {
  const float *z,*Wz,*bz,*cU1,*cb1,*cW2,*cU2,*cb2,*Wcd,*bcd;
  const float *dW1,*dU1,*db1,*dW2,*dU2,*db2,*Wp,*bp;
  float *zT,*sT,*ggate,*h1cT,*ceT,*sdT,*beffP,*db1P,*db2P,*WEp,*out;
  uint *WAh,*WAl,*WBh,*WBl,*h1pk,*h2pk,*dh1pk,*dh2pk;
  int  *accI;
};

// ---- barrier state ----
__device__ unsigned g_cnt_l1[16 * 32];
__device__ unsigned g_cnt;
__device__ unsigned g_gen;
__device__ unsigned pod_ctr[8 * 64];   // monotonic per-pod arrival counter

__device__ __forceinline__ float sigm(float x) { return 1.0f / (1.0f + __expf(-x)); }

__device__ __forceinline__ float aloadF(const float* p) {
  return __hip_atomic_load(p, __ATOMIC_RELAXED, __HIP_MEMORY_SCOPE_AGENT);
}
__device__ __forceinline__ void astoreF(float* p, float v) {
  __hip_atomic_store(p, v, __ATOMIC_RELAXED, __HIP_MEMORY_SCOPE_AGENT);
}
__device__ __forceinline__ uint aloadU(const uint* p) {
  return __hip_atomic_load(p, __ATOMIC_RELAXED, __HIP_MEMORY_SCOPE_AGENT);
}
__device__ __forceinline__ void astoreU(uint* p, uint v) {
  __hip_atomic_store(p, v, __ATOMIC_RELAXED, __HIP_MEMORY_SCOPE_AGENT);
}
__device__ __forceinline__ int aloadI(const int* p) {
  return __hip_atomic_load(p, __ATOMIC_RELAXED, __HIP_MEMORY_SCOPE_AGENT);
}

// split v = hi + lo (both bf16, RNE)
__device__ __forceinline__ void split2(float v, unsigned short& h, unsigned short& l) {
  __hip_bfloat16 bh = __float2bfloat16(v);
  float hf = __bfloat162float(bh);
  __hip_bfloat16 bl = __float2bfloat16(v - hf);
  h = *(unsigned short*)&bh; l = *(unsigned short*)&bl;
}
__device__ __forceinline__ uint packsplit(float v) {
  unsigned short h, l; split2(v, h, l);
  return (uint)h | ((uint)l << 16);
}

// global barrier (preamble only)
__device__ __forceinline__ void gbar() {
  __syncthreads();
  if (threadIdx.x == 0) {
    asm volatile("s_waitcnt vmcnt(0)" ::: "memory");
    unsigned g0 = __hip_atomic_load(&g_gen, __ATOMIC_RELAXED, __HIP_MEMORY_SCOPE_AGENT);
    unsigned p1 = __hip_atomic_fetch_add(&g_cnt_l1[(blockIdx.x >> 4) * 32], 1u,
                                         __ATOMIC_RELAXED, __HIP_MEMORY_SCOPE_AGENT);
    if (p1 == 15u) {
      unsigned p2 = __hip_atomic_fetch_add(&g_cnt, 1u, __ATOMIC_RELAXED, __HIP_MEMORY_SCOPE_AGENT);
      if (p2 == 15u) {
        #pragma unroll
        for (int i = 0; i < 16; i++)
          __hip_atomic_store(&g_cnt_l1[i * 32], 0u, __ATOMIC_RELAXED, __HIP_MEMORY_SCOPE_AGENT);
        __hip_atomic_store(&g_cnt, 0u, __ATOMIC_RELAXED, __HIP_MEMORY_SCOPE_AGENT);
        asm volatile("s_waitcnt vmcnt(0)" ::: "memory");
        __hip_atomic_fetch_add(&g_gen, 1u, __ATOMIC_RELAXED, __HIP_MEMORY_SCOPE_AGENT);
      }
    }
    while (__hip_atomic_load(&g_gen, __ATOMIC_RELAXED, __HIP_MEMORY_SCOPE_AGENT) == g0)
      __builtin_amdgcn_s_sleep(1);
  }
  __syncthreads();
}

// monotonic pod barrier: 1 atomic arrival, poll same line until all 32 arrived.
// tgt is per-block running target (base read once per launch before any arrival).
__device__ __forceinline__ void pbar2(int pod, unsigned& tgt) {
  __syncthreads();
  if (threadIdx.x == 0) {
    asm volatile("s_waitcnt vmcnt(0)" ::: "memory");
    unsigned* ctr = &pod_ctr[pod * 64];
    __hip_atomic_fetch_add(ctr, 1u, __ATOMIC_RELAXED, __HIP_MEMORY_SCOPE_AGENT);
    while ((int)(__hip_atomic_load(ctr, __ATOMIC_RELAXED, __HIP_MEMORY_SCOPE_AGENT) - tgt) < 0) { }
  }
  __syncthreads();
  tgt += 32;
}

// ---------------- preamble f32 helpers (rounds 4-7 proven) ----------------
__device__ __forceinline__ void stageN(float* __restrict__ xs, const float* __restrict__ X,
                                       int nrows, int b0, int tid) {
  for (int i = tid; i < nrows * 16; i += NTHR)
    xs[i] = aloadF(X + (size_t)(i >> 4) * Bn + b0 + (i & 15));
}

template<int KC>
__device__ __forceinline__ void gemm16(const float* __restrict__ Wb, int colbase,
                                       int kq, int cg, int bg,
                                       const float* __restrict__ xsrc, float acc[16]) {
  const float* wp = Wb + (size_t)(kq * KC) * NGn + colbase + cg * 4;
  const float* xp = xsrc + (kq * KC) * 16 + bg * 4;
  #pragma unroll 2
  for (int kk = 0; kk < KC; kk++) {
    const float4 w4 = *(const float4*)(wp);
    const float4 x4 = *(const float4*)(xp);
    acc[0]  = fmaf(w4.x, x4.x, acc[0]);  acc[1]  = fmaf(w4.x, x4.y, acc[1]);
    acc[2]  = fmaf(w4.x, x4.z, acc[2]);  acc[3]  = fmaf(w4.x, x4.w, acc[3]);
    acc[4]  = fmaf(w4.y, x4.x, acc[4]);  acc[5]  = fmaf(w4.y, x4.y, acc[5]);
    acc[6]  = fmaf(w4.y, x4.z, acc[6]);  acc[7]  = fmaf(w4.y, x4.w, acc[7]);
    acc[8]  = fmaf(w4.z, x4.x, acc[8]);  acc[9]  = fmaf(w4.z, x4.y, acc[9]);
    acc[10] = fmaf(w4.z, x4.z, acc[10]); acc[11] = fmaf(w4.z, x4.w, acc[11]);
    acc[12] = fmaf(w4.w, x4.x, acc[12]); acc[13] = fmaf(w4.w, x4.y, acc[13]);
    acc[14] = fmaf(w4.w, x4.z, acc[14]); acc[15] = fmaf(w4.w, x4.w, acc[15]);
    wp += NGn; xp += 16;
  }
}

__device__ __forceinline__ void pstore(float* __restrict__ part, int kq, int cg, int bg,
                                       const float acc[16]) {
  #pragma unroll
  for (int c = 0; c < 4; c++) {
    float* p = part + (size_t)(kq * 64 + cg * 4 + c) * 17 + bg * 4;
    *(float4*)p = make_float4(acc[c*4], acc[c*4+1], acc[c*4+2], acc[c*4+3]);
  }
}

template<int MODE>
__device__ __forceinline__ void epi_plain(const float* bias, float* out,
                                          int colbase, int b0, int tid,
                                          const float* __restrict__ part) {
  int cl = tid >> 4, bl = tid & 15;
  float s = 0.0f;
  #pragma unroll
  for (int w = 0; w < 8; w++) s += part[(w * 64 + cl) * 17 + bl];
  if (bias) s += bias[colbase + cl];
  if (MODE == 0) s = tanhf(s);
  astoreF(out + (size_t)(colbase + cl) * Bn + b0 + bl, s);
}

__device__ __forceinline__ void cond_nl(const float* gb, const float* cbias,
                                        const float* cin, float* hout, int bid, int tid) {
  int i = bid * NTHR + tid;
  if (i < 512 * Bn) {
    int hid = i >> 7, b = i & 127;
    float gi = aloadF(gb + (size_t)hid * Bn + b)            + cbias[hid];
    float gf = aloadF(gb + (size_t)(512 + hid) * Bn + b)    + cbias[512 + hid];
    float gg = aloadF(gb + (size_t)(1024 + hid) * Bn + b)   + cbias[1024 + hid];
    float go = aloadF(gb + (size_t)(1536 + hid) * Bn + b)   + cbias[1536 + hid];
    float cprev = aloadF(cin + (size_t)hid * Bn + b);
    float c = sigm(gf) * cprev + sigm(gi) * tanhf(gg);
    astoreF(hout + (size_t)hid * Bn + b, sigm(go) * tanhf(c));
  }
}

// ---------------- main-loop MFMA machinery ----------------
// frag maps (rounds 5-7 verified): A(x): m=lane&15, k=(lane>>4)*8+e.
// B(w): n=lane&15, k=(lane>>4)*8+e. D: n=lane&15, m=(lane>>4)*4+reg.
// k-major packed x (global): value uint at x[k*128 + b] -> lane-coalesced.
__device__ __forceinline__ void ldxK(const uint* __restrict__ base, FR& xh, FR& xl) {
  uint w[8];
  #pragma unroll
  for (int e = 0; e < 8; e++) w[e] = aloadU(base + e * 128);
  xh.u[0] = (w[0] & 0xffffu) | (w[1] << 16); xl.u[0] = (w[0] >> 16) | (w[1] & 0xffff0000u);
  xh.u[1] = (w[2] & 0xffffu) | (w[3] << 16); xl.u[1] = (w[2] >> 16) | (w[3] & 0xffff0000u);
  xh.u[2] = (w[4] & 0xffffu) | (w[5] << 16); xl.u[2] = (w[4] >> 16) | (w[5] & 0xffff0000u);
  xh.u[3] = (w[6] & 0xffffu) | (w[7] << 16); xl.u[3] = (w[6] >> 16) | (w[7] & 0xffff0000u);
}
// LDS note tile: row stride 17 uints
__device__ __forceinline__ void ldxL17(const uint* __restrict__ p, FR& xh, FR& xl) {
  uint w[8];
  #pragma unroll
  for (int e = 0; e < 8; e++) w[e] = p[e * 17];
  xh.u[0] = (w[0] & 0xffffu) | (w[1] << 16); xl.u[0] = (w[0] >> 16) | (w[1] & 0xffff0000u);
  xh.u[1] = (w[2] & 0xffffu) | (w[3] << 16); xl.u[1] = (w[2] >> 16) | (w[3] & 0xffff0000u);
  xh.u[2] = (w[4] & 0xffffu) | (w[5] << 16); xl.u[2] = (w[4] >> 16) | (w[5] & 0xffff0000u);
  xh.u[3] = (w[6] & 0xffffu) | (w[7] << 16); xl.u[3] = (w[6] >> 16) | (w[7] & 0xffff0000u);
}

struct MC {
  const uint *WAh,*WAl,*WBh,*WBl,*dh1pk,*dh2pk;
  uint *h1pk,*h2pk;
  const float *beffP,*db2P,*Wp,*bp;
  int *accI;                      // pod-sliced: + par*ACC_PAR + bl*192 + o
  float *out;
  uint *NTu;                      // LDS note: 192 x 17
  float *plog,*gbuf,*cst,*h2s;    // LDS
  int j, b0;
};

#define MFMA3(ACC, XH, XL, WH, WL)                                            \
  ACC = __builtin_amdgcn_mfma_f32_16x16x32_bf16(XH.s, WH.s, ACC, 0, 0, 0);    \
  ACC = __builtin_amdgcn_mfma_f32_16x16x32_bf16(XL.s, WH.s, ACC, 0, 0, 0);    \
  ACC = __builtin_amdgcn_mfma_f32_16x16x32_bf16(XH.s, WL.s, ACC, 0, 0, 0);

// phase A: [softmax(t-1) from accI -> NTu + out(t-1)] then decoder L1
__device__ __forceinline__ void phaseA(const MC& c, int t, bool doLSTM) {
  const int tid = threadIdx.x, wid = tid >> 6, lane = tid & 63;
  const int m = lane & 15, kh = lane >> 4;
  const int par = t & 1; const bool rst = (t & 15) == 0;
  // ---- front: in-register per-wave softmax; wave = batch ----
  if (t > 0) {
    const int wv = wid;
    const int* ai = c.accI + ((par ^ 1) * ACC_PAR) + wv * 192;
    float lg[3], pv[3];
    #pragma unroll
    for (int rep = 0; rep < 3; rep++) {
      int o = lane + rep * 64;
      lg[rep] = (o < DOn) ? (float)aloadI(ai + o) * (1.0f / 1048576.0f) + c.bp[o] : -1e30f;
    }
    float mx = fmaxf(fmaxf(lg[0], lg[1]), lg[2]);
    #pragma unroll
    for (int d = 1; d < 64; d <<= 1) mx = fmaxf(mx, __shfl_xor(mx, d));
    float sum = 0.f;
    #pragma unroll
    for (int rep = 0; rep < 3; rep++) {
      int o = lane + rep * 64;
      pv[rep] = (o < DOn) ? __expf(lg[rep] - mx) : 0.f;
      sum += pv[rep];
    }
    #pragma unroll
    for (int d = 1; d < 64; d <<= 1) sum += __shfl_xor(sum, d);
    const float inv = 1.0f / sum;
    #pragma unroll
    for (int rep = 0; rep < 3; rep++) {
      int o = lane + rep * 64;
      float p = pv[rep] * inv;
      c.NTu[o * 17 + wv] = (o < DOn) ? packsplit(p) : 0u;
      if (c.j < 16 && wv == c.j && o < DOn)
        c.out[((size_t)(c.b0 + c.j) * TTn + (t - 1)) * DOn + o] = p;
    }
  }
  __syncthreads();
  if (!doLSTM) return;
  // ---- decoder L1 (K=704: note ks 0..5 from NTu LDS, h1 ks 6..21 from global) ----
  const int nt = wid & 3, ksq = wid >> 2;
  const int s0 = (ksq == 0) ? 0 : (ksq == 1) ? 6 : (ksq == 2) ? 12 : 17;
  const int s1 = (ksq == 0) ? 6 : (ksq == 1) ? 12 : (ksq == 2) ? 17 : 22;
  const uint* hb = (rst ? c.dh1pk : (c.h1pk + (par ^ 1) * HPAR)) + kh * 8 * 128 + c.b0 + m;
  f32x4 acc = {0.f,0.f,0.f,0.f};
  for (int ks = s0; ks < s1; ks++) {
    FR xh, xl;
    if (ks < 6) ldxL17(c.NTu + (ks * 32 + kh * 8) * 17 + m, xh, xl);
    else        ldxK(hb + (ks * 32 - 192) * 128, xh, xl);
    FR wh, wl;
    *(uint4*)wh.u = *(const uint4*)(c.WAh + (size_t)c.j * 22528 + (ks * 4 + nt) * 256 + lane * 4);
    *(uint4*)wl.u = *(const uint4*)(c.WAl + (size_t)c.j * 22528 + (ks * 4 + nt) * 256 + lane * 4);
    MFMA3(acc, xh, xl, wh, wl)
  }
  #pragma unroll
  for (int r = 0; r < 4; r++) c.plog[((ksq * 4 + nt) * 4 + r) * 64 + lane] = acc[r];
  __syncthreads();
  {
    int cl = tid >> 4, bl = tid & 15;
    float s = 0.f;
    #pragma unroll
    for (int k2 = 0; k2 < 4; k2++)
      s += c.plog[((k2 * 4 + (cl >> 4)) * 4 + (bl & 3)) * 64 + (bl >> 2) * 16 + (cl & 15)];
    c.gbuf[cl * 16 + bl] = s + c.beffP[(size_t)(c.j * 64 + cl) * Bn + c.b0 + bl];
  }
  __syncthreads();
  if (tid < 256) {
    int h = tid >> 4, bl = tid & 15;
    float gi = c.gbuf[(h*4+0)*16+bl], gf = c.gbuf[(h*4+1)*16+bl];
    float gg = c.gbuf[(h*4+2)*16+bl], go = c.gbuf[(h*4+3)*16+bl];
    float cp = rst ? c.cst[512 + tid] : c.cst[tid];
    float cc = sigm(gf) * cp + sigm(gi) * tanhf(gg);
    c.cst[tid] = cc;
    astoreU(c.h1pk + par * HPAR + (size_t)(c.j * 16 + h) * 128 + c.b0 + bl,
            packsplit(sigm(go) * tanhf(cc)));
  }
}

// phase B: decoder L2 (K=1024) + partial logits -> int32 atomicAdd + zero other parity
__device__ __forceinline__ void phaseB(const MC& c, int t) {
  const int tid = threadIdx.x, wid = tid >> 6, lane = tid & 63;
  const int m = lane & 15, kh = lane >> 4;
  const int nt = wid & 3, ksq = wid >> 2;
  const int par = t & 1; const bool rst = (t & 15) == 0;
  const uint* s1b = c.h1pk + par * HPAR + kh * 8 * 128 + c.b0 + m;
  const uint* s2b = (rst ? c.dh2pk : (c.h2pk + (par ^ 1) * HPAR)) + kh * 8 * 128 + c.b0 + m;
  f32x4 acc = {0.f,0.f,0.f,0.f};
  #pragma unroll
  for (int kk = 0; kk < 8; kk++) {
    const int ks = ksq * 8 + kk;
    FR xh, xl;
    if (ksq < 2) ldxK(s1b + ks * 32 * 128, xh, xl);
    else         ldxK(s2b + (ks - 16) * 32 * 128, xh, xl);
    FR wh, wl;
    *(uint4*)wh.u = *(const uint4*)(c.WBh + (size_t)c.j * 32768 + (ks * 4 + nt) * 256 + lane * 4);
    *(uint4*)wl.u = *(const uint4*)(c.WBl + (size_t)c.j * 32768 + (ks * 4 + nt) * 256 + lane * 4);
    MFMA3(acc, xh, xl, wh, wl)
  }
  #pragma unroll
  for (int r = 0; r < 4; r++) c.plog[((ksq * 4 + nt) * 4 + r) * 64 + lane] = acc[r];
  __syncthreads();
  {
    int cl = tid >> 4, bl = tid & 15;
    float s = 0.f;
    #pragma unroll
    for (int k2 = 0; k2 < 4; k2++)
      s += c.plog[((k2 * 4 + (cl >> 4)) * 4 + (bl & 3)) * 64 + (bl >> 2) * 16 + (cl & 15)];
    c.gbuf[cl * 16 + bl] = s + c.db2P[c.j * 64 + cl];
  }
  __syncthreads();
  if (tid < 256) {
    int h = tid >> 4, bl = tid & 15;
    float gi = c.gbuf[(h*4+0)*16+bl], gf = c.gbuf[(h*4+1)*16+bl];
    float gg = c.gbuf[(h*4+2)*16+bl], go = c.gbuf[(h*4+3)*16+bl];
    float cp = rst ? c.cst[768 + tid] : c.cst[256 + tid];
    float cc = sigm(gf) * cp + sigm(gi) * tanhf(gg);
    c.cst[256 + tid] = cc;
    float h2v = sigm(go) * tanhf(cc);
    c.h2s[h * 16 + bl] = h2v;
    astoreU(c.h2pk + par * HPAR + (size_t)(c.j * 16 + h) * 128 + c.b0 + bl, packsplit(h2v));
  }
  __syncthreads();
  // partial projection logits over this block's 16-hid slice -> fixed-point atomic add
  const int o = tid & 255, q = tid >> 8;
  if (o < DOn) {
    float wv[16];
    #pragma unroll
    for (int h = 0; h < 16; h++) wv[h] = c.Wp[(size_t)(c.j * 16 + h) * DOn + o];
    #pragma unroll
    for (int rep = 0; rep < 4; rep++) {
      const int bl = q * 4 + rep;
      float s = 0.f;
      #pragma unroll
      for (int h = 0; h < 16; h++) s = fmaf(c.h2s[h * 16 + bl], wv[h], s);
      __hip_atomic_fetch_add(c.accI + par * ACC_PAR + bl * 192 + o,
                             __float2int_rn(s * 1048576.0f),
                             __ATOMIC_RELAXED, __HIP_MEMORY_SCOPE_AGENT);
    }
  }
  // zero the other-parity slice (consumed by phase A earlier this step)
  if (tid < 96)
    astoreU((uint*)(c.accI + (par ^ 1) * ACC_PAR + c.j * 96 + tid), 0u);
}

// ---------------- kernel ----------------
__global__ void __launch_bounds__(NTHR, 1)
hd_kernel(KA A) {
  __shared__ float buf[25088];   // preamble: xs[16384]+part[8704]; main: NTu/plog/gbuf/cst/h2s
  float* xs = buf;
  float* part = buf + 16384;
  const int bid = blockIdx.x, tid = threadIdx.x;
  const int lane = tid & 63;
  const int kqP = tid >> 6, cgP = lane & 15, bgP = lane >> 4;   // preamble gemm (tid<512)
  const int rP = bid & 31, btP = bid >> 5;
  const int htP = (rP & 7) * 4 + (rP >> 3);
  const int colbaseP = htP * 64, b0P = btP * 16;
  const int pod = bid >> 5;

  // read monotonic barrier base BEFORE any pod activity this launch
  unsigned tgt = __hip_atomic_load(&pod_ctr[pod * 64], __ATOMIC_RELAXED,
                                   __HIP_MEMORY_SCOPE_AGENT) + 32;

  // ---- P-1: z transpose, bias perms, WEp, WA pack, accI zero ----
  {
    const int i0 = bid * NTHR + tid;                 // 0..262143
    if (i0 < 512 * Bn) { int zb = i0 >> 9, zk = i0 & 511; astoreF(A.zT + (size_t)zk * Bn + zb, A.z[i0]); }
    if (i0 < NGn) {
      int hid = i0 >> 2, g = i0 & 3, sc = g * 512 + hid;
      astoreF(A.db1P + i0, A.db1[sc]);
      astoreF(A.db2P + i0, A.db2[sc]);
    }
    if (i0 < 2 * ACC_PAR) astoreU((uint*)(A.accI + i0), 0u);
    for (int i = i0; i < 512 * NGn; i += NBLK * NTHR) {   // WEp[k][cp]
      int k = i >> 11, pc = i & 2047;
      int hid = pc >> 2, g = pc & 3;
      astoreF(A.WEp + i, A.dW1[(size_t)(176 + k) * NGn + g * 512 + hid]);
    }
    for (int i = i0; i < 720896; i += NBLK * NTHR) {      // WA frag planes
      int col = i & 2047, kp = i >> 11, k = kp * 2;
      float w0, w1;
      if (k < 176)      { w0 = A.dW1[(size_t)k * NGn + col];       w1 = A.dW1[(size_t)(k + 1) * NGn + col]; }
      else if (k < 192) { w0 = 0.f; w1 = 0.f; }
      else              { w0 = A.dU1[(size_t)(k - 192) * NGn + col]; w1 = A.dU1[(size_t)(k - 191) * NGn + col]; }
      unsigned short h0, l0, h1, l1; split2(w0, h0, l0); split2(w1, h1, l1);
      int g = col >> 9, hid = col & 511;
      int jj = hid >> 4, cl = (hid & 15) * 4 + g;
      int nt = cl >> 4, n = cl & 15;
      int ks = k >> 5, kr = k & 31, lh = kr >> 3, q = (kr >> 1) & 3;
      int idx = ((jj * 22 + ks) * 4 + nt) * 256 + (lh * 16 + n) * 4 + q;
      astoreU(A.WAh + idx, (uint)h0 | ((uint)h1 << 16));
      astoreU(A.WAl + idx, (uint)l0 | ((uint)l1 << 16));
    }
  }
  gbar();
  // ---- pre0: sT = tanh(z @ Wz + bz) ----
  {
    stageN(xs, A.zT, 512, b0P, tid); __syncthreads();
    if (tid < 512) {
      float acc[16] = {0,0,0,0,0,0,0,0,0,0,0,0,0,0,0,0};
      gemm16<64>(A.Wz, colbaseP, kqP, cgP, bgP, xs, acc);
      pstore(part, kqP, cgP, bgP, acc);
    }
    __syncthreads();
    epi_plain<0>(A.bz, A.sT, colbaseP, b0P, tid, part);
  }
  gbar();
  // ---- pre1: conductor L1 gates ----
  {
    stageN(xs, A.sT, 512, b0P, tid); __syncthreads();
    if (tid < 512) {
      float acc[16] = {0,0,0,0,0,0,0,0,0,0,0,0,0,0,0,0};
      gemm16<64>(A.cU1, colbaseP, kqP, cgP, bgP, xs, acc);
      pstore(part, kqP, cgP, bgP, acc);
    }
    __syncthreads();
    epi_plain<1>(nullptr, A.ggate, colbaseP, b0P, tid, part);
  }
  gbar();
  cond_nl(A.ggate, A.cb1, A.sT + (size_t)512 * Bn, A.h1cT, bid, tid);
  gbar();
  // ---- pre2: conductor L2 gates ----
  {
    stageN(xs, A.h1cT, 512, b0P, tid);
    stageN(xs + 8192, A.sT + (size_t)1024 * Bn, 512, b0P, tid);
    __syncthreads();
    if (tid < 512) {
      float acc[16] = {0,0,0,0,0,0,0,0,0,0,0,0,0,0,0,0};
      gemm16<64>(A.cW2, colbaseP, kqP, cgP, bgP, xs, acc);
      gemm16<64>(A.cU2, colbaseP, kqP, cgP, bgP, xs + 8192, acc);
      pstore(part, kqP, cgP, bgP, acc);
    }
    __syncthreads();
    epi_plain<1>(nullptr, A.ggate, colbaseP, b0P, tid, part);
  }
  gbar();
  cond_nl(A.ggate, A.cb2, A.sT + (size_t)1536 * Bn, A.ceT, bid, tid);
  gbar();
  // ---- pre3: sdT = tanh(ce @ Wcd + bcd); beffP = db1P + ce @ WEp ----
  {
    stageN(xs, A.ceT, 512, b0P, tid); __syncthreads();
    if (tid < 512) {
      float acc[16] = {0,0,0,0,0,0,0,0,0,0,0,0,0,0,0,0};
      gemm16<64>(A.Wcd, colbaseP, kqP, cgP, bgP, xs, acc);
      pstore(part, kqP, cgP, bgP, acc);
    }
    __syncthreads();
    epi_plain<0>(A.bcd, A.sdT, colbaseP, b0P, tid, part);
    __syncthreads();
    if (tid < 512) {
      float acc[16] = {0,0,0,0,0,0,0,0,0,0,0,0,0,0,0,0};
      gemm16<64>(A.WEp, colbaseP, kqP, cgP, bgP, xs, acc);
      pstore(part, kqP, cgP, bgP, acc);
    }
    __syncthreads();
    epi_plain<1>(A.db1P, A.beffP, colbaseP, b0P, tid, part);
  }
  gbar();
  // ---- P4: WB pack (overwrites WEp) + dh packs (k-major) ----
  {
    const int i0 = bid * NTHR + tid;
    for (int i = i0; i < 1048576; i += NBLK * NTHR) {
      int col = i & 2047, kp = i >> 11, k = kp * 2;
      float w0, w1;
      if (k < 512) { w0 = A.dW2[(size_t)k * NGn + col];         w1 = A.dW2[(size_t)(k + 1) * NGn + col]; }
      else         { w0 = A.dU2[(size_t)(k - 512) * NGn + col]; w1 = A.dU2[(size_t)(k - 511) * NGn + col]; }
      unsigned short h0, l0, h1, l1; split2(w0, h0, l0); split2(w1, h1, l1);
      int g = col >> 9, hid = col & 511;
      int jj = hid >> 4, cl = (hid & 15) * 4 + g;
      int nt = cl >> 4, n = cl & 15;
      int ks = k >> 5, kr = k & 31, lh = kr >> 3, q = (kr >> 1) & 3;
      int idx = ((jj * 32 + ks) * 4 + nt) * 256 + (lh * 16 + n) * 4 + q;
      astoreU(A.WBh + idx, (uint)h0 | ((uint)h1 << 16));
      astoreU(A.WBl + idx, (uint)l0 | ((uint)l1 << 16));
    }
    if (i0 < 512 * Bn) {
      int hid = i0 >> 7, b = i0 & 127;
      astoreU(A.dh1pk + hid * 128 + b, packsplit(aloadF(A.sdT + (size_t)hid * Bn + b)));
      astoreU(A.dh2pk + hid * 128 + b, packsplit(aloadF(A.sdT + (size_t)(1024 + hid) * Bn + b)));
    }
  }
  gbar();

  // ---- main loop ----
  MC c;
  c.WAh = A.WAh; c.WAl = A.WAl; c.WBh = A.WBh; c.WBl = A.WBl;
  c.dh1pk = A.dh1pk; c.dh2pk = A.dh2pk;
  c.h1pk = A.h1pk; c.h2pk = A.h2pk;
  c.beffP = A.beffP; c.db2P = A.db2P; c.Wp = A.Wp; c.bp = A.bp; c.out = A.out;
  c.accI = A.accI + pod * 3072;
  c.NTu = (uint*)buf;            // 192 x 17 = 3264
  c.plog = buf + 3264;           // 4096
  c.gbuf = buf + 7360;           // 1024
  c.cst  = buf + 8384;           // 1024
  c.h2s  = buf + 9408;           // 256
  c.j = bid & 31;
  c.b0 = pod * 16;
  if (tid < 256) {
    int h = tid >> 4, bl = tid & 15;
    c.cst[512 + tid] = aloadF(A.sdT + (size_t)(512 + c.j * 16 + h) * Bn + c.b0 + bl);
    c.cst[768 + tid] = aloadF(A.sdT + (size_t)(1536 + c.j * 16 + h) * Bn + c.b0 + bl);
  }
  for (int i = tid; i < 3264; i += NTHR) c.NTu[i] = 0u;   // note(0) = 0 + pad rows
  __syncthreads();

  for (int t = 0; t < TTn; t++) {
    phaseA(c, t, true);
    pbar2(pod, tgt);
    phaseB(c, t);
    pbar2(pod, tgt);
  }
  phaseA(c, TTn, false);   // final softmax -> out[255]
}

extern "C" void kernel_launch(void* const* d_in, const int* in_sizes, int n_in,
                              void* d_out, int out_size, void* d_ws, size_t ws_size,
                              hipStream_t stream) {
  (void)in_sizes; (void)n_in; (void)out_size; (void)ws_size;
  KA a;
  a.z   = (const float*)d_in[0];
  a.Wz  = (const float*)d_in[3];  a.bz  = (const float*)d_in[4];
  // d_in[5] = cond_W1 unused (conductor input x0 == 0)
  a.cU1 = (const float*)d_in[6];  a.cb1 = (const float*)d_in[7];
  a.cW2 = (const float*)d_in[8];  a.cU2 = (const float*)d_in[9];  a.cb2 = (const float*)d_in[10];
  a.Wcd = (const float*)d_in[11]; a.bcd = (const float*)d_in[12];
  a.dW1 = (const float*)d_in[13]; a.dU1 = (const float*)d_in[14]; a.db1 = (const float*)d_in[15];
  a.dW2 = (const float*)d_in[16]; a.dU2 = (const float*)d_in[17]; a.db2 = (const float*)d_in[18];
  a.Wp  = (const float*)d_in[19]; a.bp  = (const float*)d_in[20];

  float* ws = (float*)d_ws;
  size_t off = 0;
  a.zT    = ws + off; off += (size_t)512  * Bn;
  a.sT    = ws + off; off += (size_t)NGn  * Bn;
  a.ggate = ws + off; off += (size_t)NGn  * Bn;
  a.h1cT  = ws + off; off += (size_t)512  * Bn;
  a.ceT   = ws + off; off += (size_t)512  * Bn;
  a.sdT   = ws + off; off += (size_t)NGn  * Bn;       // dh1|dc1|dh2|dc2
  a.beffP = ws + off; off += (size_t)NGn  * Bn;       // [cp][b]
  a.db1P  = ws + off; off += (size_t)NGn;
  a.db2P  = ws + off; off += (size_t)NGn;
  a.WEp   = ws + off; off += (size_t)512 * NGn;       // aliased by WBh in P4
  a.WBh   = (uint*)a.WEp;
  a.WBl   = (uint*)(ws + off); off += (size_t)1048576;
  a.WAh   = (uint*)(ws + off); off += (size_t)720896;
  a.WAl   = (uint*)(ws + off); off += (size_t)720896;
  a.h1pk  = (uint*)(ws + off); off += (size_t)2 * HPAR;
  a.h2pk  = (uint*)(ws + off); off += (size_t)2 * HPAR;
  a.dh1pk = (uint*)(ws + off); off += (size_t)HPAR;
  a.dh2pk = (uint*)(ws + off); off += (size_t)HPAR;
  a.accI  = (int*)(ws + off);  off += (size_t)2 * ACC_PAR;
  a.out   = (float*)d_out;

  hd_kernel<<<dim3(NBLK), dim3(NTHR), 0, stream>>>(a);
}

// Round 11
// 7156.149 us; speedup vs baseline: 1.3139x; 1.0862x over previous
//
#include <hip/hip_runtime.h>
#include <hip/hip_bf16.h>
#include <math.h>

// ---- dims ----
#define Bn    128
#define NGn   2048
#define TTn   256
#define DOn   176
#define NBLK  256
#define NTHR  1024
#define HPAR  65536          // 512*128 uints per parity, layout [k/8][128 b][8]
#define ACC_PAR 24576        // ints per parity in accI (8 pods x 16 b x 192)

typedef unsigned int uint;
typedef unsigned long long u64;
using f32x4 = __attribute__((ext_vector_type(4))) float;
using s16x8 = __attribute__((ext_vector_type(8))) short;
union FR { uint u[4]; s16x8 s; };

struct KA {
  const float *z,*Wz,*bz,*cU1,*cb1,*cW2,*cU2,*cb2,*Wcd,*bcd;
  const float *dW1,*dU1,*db1,*dW2,*dU2,*db2,*Wp,*bp;
  float *zT,*sT,*ggate,*h1cT,*ceT,*sdT,*beffP,*db1P,*db2P,*WEp,*out;
  uint *WAh,*WAl,*WBh,*WBl,*h1pk,*h2pk,*dh1pk,*dh2pk;
  int  *accI;
};

// ---- barrier state ----
__device__ unsigned g_cnt_l1[16 * 32];
__device__ unsigned g_cnt;
__device__ unsigned g_gen;
__device__ unsigned pod_ctr[8 * 64];   // monotonic per-pod arrival counter

__device__ __forceinline__ float sigm(float x) { return 1.0f / (1.0f + __expf(-x)); }

__device__ __forceinline__ float aloadF(const float* p) {
  return __hip_atomic_load(p, __ATOMIC_RELAXED, __HIP_MEMORY_SCOPE_AGENT);
}
__device__ __forceinline__ void astoreF(float* p, float v) {
  __hip_atomic_store(p, v, __ATOMIC_RELAXED, __HIP_MEMORY_SCOPE_AGENT);
}
__device__ __forceinline__ uint aloadU(const uint* p) {
  return __hip_atomic_load(p, __ATOMIC_RELAXED, __HIP_MEMORY_SCOPE_AGENT);
}
__device__ __forceinline__ void astoreU(uint* p, uint v) {
  __hip_atomic_store(p, v, __ATOMIC_RELAXED, __HIP_MEMORY_SCOPE_AGENT);
}
__device__ __forceinline__ int aloadI(const int* p) {
  return __hip_atomic_load(p, __ATOMIC_RELAXED, __HIP_MEMORY_SCOPE_AGENT);
}
__device__ __forceinline__ u64 aload64(const u64* p) {
  return __hip_atomic_load(p, __ATOMIC_RELAXED, __HIP_MEMORY_SCOPE_AGENT);
}

// split v = hi + lo (both bf16, RNE)
__device__ __forceinline__ void split2(float v, unsigned short& h, unsigned short& l) {
  __hip_bfloat16 bh = __float2bfloat16(v);
  float hf = __bfloat162float(bh);
  __hip_bfloat16 bl = __float2bfloat16(v - hf);
  h = *(unsigned short*)&bh; l = *(unsigned short*)&bl;
}
__device__ __forceinline__ uint packsplit(float v) {
  unsigned short h, l; split2(v, h, l);
  return (uint)h | ((uint)l << 16);
}

// global barrier (preamble only)
__device__ __forceinline__ void gbar() {
  __syncthreads();
  if (threadIdx.x == 0) {
    asm volatile("s_waitcnt vmcnt(0)" ::: "memory");
    unsigned g0 = __hip_atomic_load(&g_gen, __ATOMIC_RELAXED, __HIP_MEMORY_SCOPE_AGENT);
    unsigned p1 = __hip_atomic_fetch_add(&g_cnt_l1[(blockIdx.x >> 4) * 32], 1u,
                                         __ATOMIC_RELAXED, __HIP_MEMORY_SCOPE_AGENT);
    if (p1 == 15u) {
      unsigned p2 = __hip_atomic_fetch_add(&g_cnt, 1u, __ATOMIC_RELAXED, __HIP_MEMORY_SCOPE_AGENT);
      if (p2 == 15u) {
        #pragma unroll
        for (int i = 0; i < 16; i++)
          __hip_atomic_store(&g_cnt_l1[i * 32], 0u, __ATOMIC_RELAXED, __HIP_MEMORY_SCOPE_AGENT);
        __hip_atomic_store(&g_cnt, 0u, __ATOMIC_RELAXED, __HIP_MEMORY_SCOPE_AGENT);
        asm volatile("s_waitcnt vmcnt(0)" ::: "memory");
        __hip_atomic_fetch_add(&g_gen, 1u, __ATOMIC_RELAXED, __HIP_MEMORY_SCOPE_AGENT);
      }
    }
    while (__hip_atomic_load(&g_gen, __ATOMIC_RELAXED, __HIP_MEMORY_SCOPE_AGENT) == g0)
      __builtin_amdgcn_s_sleep(1);
  }
  __syncthreads();
}

// monotonic pod barrier (round-10 proven)
__device__ __forceinline__ void pbar2(int pod, unsigned& tgt) {
  __syncthreads();
  if (threadIdx.x == 0) {
    asm volatile("s_waitcnt vmcnt(0)" ::: "memory");
    unsigned* ctr = &pod_ctr[pod * 64];
    __hip_atomic_fetch_add(ctr, 1u, __ATOMIC_RELAXED, __HIP_MEMORY_SCOPE_AGENT);
    while ((int)(__hip_atomic_load(ctr, __ATOMIC_RELAXED, __HIP_MEMORY_SCOPE_AGENT) - tgt) < 0) { }
  }
  __syncthreads();
  tgt += 32;
}

// ---------------- preamble f32 helpers (rounds 4-10 proven) ----------------
__device__ __forceinline__ void stageN(float* __restrict__ xs, const float* __restrict__ X,
                                       int nrows, int b0, int tid) {
  for (int i = tid; i < nrows * 16; i += NTHR)
    xs[i] = aloadF(X + (size_t)(i >> 4) * Bn + b0 + (i & 15));
}

template<int KC>
__device__ __forceinline__ void gemm16(const float* __restrict__ Wb, int colbase,
                                       int kq, int cg, int bg,
                                       const float* __restrict__ xsrc, float acc[16]) {
  const float* wp = Wb + (size_t)(kq * KC) * NGn + colbase + cg * 4;
  const float* xp = xsrc + (kq * KC) * 16 + bg * 4;
  #pragma unroll 2
  for (int kk = 0; kk < KC; kk++) {
    const float4 w4 = *(const float4*)(wp);
    const float4 x4 = *(const float4*)(xp);
    acc[0]  = fmaf(w4.x, x4.x, acc[0]);  acc[1]  = fmaf(w4.x, x4.y, acc[1]);
    acc[2]  = fmaf(w4.x, x4.z, acc[2]);  acc[3]  = fmaf(w4.x, x4.w, acc[3]);
    acc[4]  = fmaf(w4.y, x4.x, acc[4]);  acc[5]  = fmaf(w4.y, x4.y, acc[5]);
    acc[6]  = fmaf(w4.y, x4.z, acc[6]);  acc[7]  = fmaf(w4.y, x4.w, acc[7]);
    acc[8]  = fmaf(w4.z, x4.x, acc[8]);  acc[9]  = fmaf(w4.z, x4.y, acc[9]);
    acc[10] = fmaf(w4.z, x4.z, acc[10]); acc[11] = fmaf(w4.z, x4.w, acc[11]);
    acc[12] = fmaf(w4.w, x4.x, acc[12]); acc[13] = fmaf(w4.w, x4.y, acc[13]);
    acc[14] = fmaf(w4.w, x4.z, acc[14]); acc[15] = fmaf(w4.w, x4.w, acc[15]);
    wp += NGn; xp += 16;
  }
}

__device__ __forceinline__ void pstore(float* __restrict__ part, int kq, int cg, int bg,
                                       const float acc[16]) {
  #pragma unroll
  for (int c = 0; c < 4; c++) {
    float* p = part + (size_t)(kq * 64 + cg * 4 + c) * 17 + bg * 4;
    *(float4*)p = make_float4(acc[c*4], acc[c*4+1], acc[c*4+2], acc[c*4+3]);
  }
}

template<int MODE>
__device__ __forceinline__ void epi_plain(const float* bias, float* out,
                                          int colbase, int b0, int tid,
                                          const float* __restrict__ part) {
  int cl = tid >> 4, bl = tid & 15;
  float s = 0.0f;
  #pragma unroll
  for (int w = 0; w < 8; w++) s += part[(w * 64 + cl) * 17 + bl];
  if (bias) s += bias[colbase + cl];
  if (MODE == 0) s = tanhf(s);
  astoreF(out + (size_t)(colbase + cl) * Bn + b0 + bl, s);
}

__device__ __forceinline__ void cond_nl(const float* gb, const float* cbias,
                                        const float* cin, float* hout, int bid, int tid) {
  int i = bid * NTHR + tid;
  if (i < 512 * Bn) {
    int hid = i >> 7, b = i & 127;
    float gi = aloadF(gb + (size_t)hid * Bn + b)            + cbias[hid];
    float gf = aloadF(gb + (size_t)(512 + hid) * Bn + b)    + cbias[512 + hid];
    float gg = aloadF(gb + (size_t)(1024 + hid) * Bn + b)   + cbias[1024 + hid];
    float go = aloadF(gb + (size_t)(1536 + hid) * Bn + b)   + cbias[1536 + hid];
    float cprev = aloadF(cin + (size_t)hid * Bn + b);
    float c = sigm(gf) * cprev + sigm(gi) * tanhf(gg);
    astoreF(hout + (size_t)hid * Bn + b, sigm(go) * tanhf(c));
  }
}

// ---------------- main-loop MFMA machinery ----------------
// frag maps (rounds 5-10 verified): A(x): m=lane&15, k=(lane>>4)*8+e.
// B(w): n=lane&15, k=(lane>>4)*8+e. D: n=lane&15, m=(lane>>4)*4+reg.
// packed-h layout: h[k>>3][b][k&7] -> lane (m,kh) reads 8 CONTIGUOUS uints.
__device__ __forceinline__ void unpack64(const u64* d, FR& xh, FR& xl) {
  #pragma unroll
  for (int q = 0; q < 4; q++) {
    uint lo = (uint)d[q], hi = (uint)(d[q] >> 32);
    xh.u[q] = (lo & 0xffffu) | (hi << 16);
    xl.u[q] = (lo >> 16) | (hi & 0xffff0000u);
  }
}
__device__ __forceinline__ void unpackU8(uint4 a, uint4 b, FR& xh, FR& xl) {
  xh.u[0] = (a.x & 0xffffu) | (a.y << 16); xl.u[0] = (a.x >> 16) | (a.y & 0xffff0000u);
  xh.u[1] = (a.z & 0xffffu) | (a.w << 16); xl.u[1] = (a.z >> 16) | (a.w & 0xffff0000u);
  xh.u[2] = (b.x & 0xffffu) | (b.y << 16); xl.u[2] = (b.x >> 16) | (b.y & 0xffff0000u);
  xh.u[3] = (b.z & 0xffffu) | (b.w << 16); xl.u[3] = (b.z >> 16) | (b.w & 0xffff0000u);
}

struct MC {
  const uint *WAh,*WAl,*WBh,*WBl,*dh1pk,*dh2pk;
  uint *h1pk,*h2pk;
  const float *beffP,*db2P,*Wp,*bp;
  int *accI;
  float *out;
  uint *NTu;                      // LDS note: [kt 0..23][b 16][8]
  float *plog,*gbuf,*cst,*h2s;    // LDS
  int j, b0;
};

#define MFMA3(ACC, XH, XL, WH, WL)                                            \
  ACC = __builtin_amdgcn_mfma_f32_16x16x32_bf16(XH.s, WH.s, ACC, 0, 0, 0);    \
  ACC = __builtin_amdgcn_mfma_f32_16x16x32_bf16(XL.s, WH.s, ACC, 0, 0, 0);    \
  ACC = __builtin_amdgcn_mfma_f32_16x16x32_bf16(XH.s, WL.s, ACC, 0, 0, 0);

// process one ks: all 4 nt tiles into acc[4]
__device__ __forceinline__ void doKS(const uint* WH, const uint* WL, int ks, int lane,
                                     const FR& xh, const FR& xl, f32x4 acc[4]) {
  #pragma unroll
  for (int nt = 0; nt < 4; nt++) {
    FR wh, wl;
    *(uint4*)wh.u = *(const uint4*)(WH + (ks * 4 + nt) * 256 + lane * 4);
    *(uint4*)wl.u = *(const uint4*)(WL + (ks * 4 + nt) * 256 + lane * 4);
    MFMA3(acc[nt], xh, xl, wh, wl)
  }
}

__device__ __forceinline__ void wrplog(const MC& c, int wid, int lane, const f32x4 acc[4]) {
  #pragma unroll
  for (int nt = 0; nt < 4; nt++)
    #pragma unroll
    for (int r = 0; r < 4; r++)
      c.plog[((wid * 4 + nt) * 4 + r) * 68 + lane] = acc[nt][r];
}

// 16-term reduce into gbuf + bias
__device__ __forceinline__ void reduce16(const MC& c, int tid, const float* biasv) {
  int cl = tid >> 4, bl = tid & 15;
  float s = 0.f;
  #pragma unroll
  for (int k2 = 0; k2 < 16; k2++)
    s += c.plog[((k2 * 4 + (cl >> 4)) * 4 + (bl & 3)) * 68 + (bl >> 2) * 16 + (cl & 15)];
  c.gbuf[cl * 16 + bl] = s + biasv[cl * 16 + bl];
}

// phase A: [softmax(t-1) from accI -> NTu + out(t-1)] then decoder L1
__device__ __forceinline__ void phaseA(const MC& c, int t, bool doLSTM,
                                       float* __restrict__ beffL) {
  const int tid = threadIdx.x, wid = tid >> 6, lane = tid & 63;
  const int m = lane & 15, kh = lane >> 4;
  const int par = t & 1; const bool rst = (t & 15) == 0;
  // ---- front: in-register per-wave softmax; wave = batch ----
  if (t > 0) {
    const int wv = wid;
    const int* ai = c.accI + ((par ^ 1) * ACC_PAR) + wv * 192;
    float lg[3], pv[3];
    #pragma unroll
    for (int rep = 0; rep < 3; rep++) {
      int o = lane + rep * 64;
      lg[rep] = (o < DOn) ? (float)aloadI(ai + o) * (1.0f / 1048576.0f) + c.bp[o] : -1e30f;
    }
    float mx = fmaxf(fmaxf(lg[0], lg[1]), lg[2]);
    #pragma unroll
    for (int d = 1; d < 64; d <<= 1) mx = fmaxf(mx, __shfl_xor(mx, d));
    float sum = 0.f;
    #pragma unroll
    for (int rep = 0; rep < 3; rep++) {
      int o = lane + rep * 64;
      pv[rep] = (o < DOn) ? __expf(lg[rep] - mx) : 0.f;
      sum += pv[rep];
    }
    #pragma unroll
    for (int d = 1; d < 64; d <<= 1) sum += __shfl_xor(sum, d);
    const float inv = 1.0f / sum;
    #pragma unroll
    for (int rep = 0; rep < 3; rep++) {
      int o = lane + rep * 64;
      float p = pv[rep] * inv;
      c.NTu[((o >> 3) * 16 + wv) * 8 + (o & 7)] = (o < DOn) ? packsplit(p) : 0u;
      if (c.j < 16 && wv == c.j && o < DOn)
        c.out[((size_t)(c.b0 + c.j) * TTn + (t - 1)) * DOn + o] = p;
    }
  }
  __syncthreads();
  if (!doLSTM) return;
  // ---- decoder L1: wave = k-slice (ksq16), all 4 nt per wave ----
  const uint* WH = c.WAh + (size_t)c.j * 22528;
  const uint* WL = c.WAl + (size_t)c.j * 22528;
  const uint* hsrc = rst ? c.dh1pk : (c.h1pk + (par ^ 1) * HPAR);
  f32x4 acc[4] = {{0,0,0,0},{0,0,0,0},{0,0,0,0},{0,0,0,0}};
  if (wid < 3) {
    // ks = 2*wid, 2*wid+1 : note from LDS
    #pragma unroll
    for (int i = 0; i < 2; i++) {
      const int ks = wid * 2 + i;
      const uint* p = c.NTu + ((ks * 4 + kh) * 16 + m) * 8;
      uint4 a = *(const uint4*)p, b = *(const uint4*)(p + 4);
      FR xh, xl; unpackU8(a, b, xh, xl);
      doKS(WH, WL, ks, lane, xh, xl, acc);
    }
  } else if (wid < 6) {
    // ks = 2*wid, 2*wid+1 in 6..11 : h1 global, upfront loads
    u64 xr[8];
    #pragma unroll
    for (int i = 0; i < 2; i++) {
      const int ks = wid * 2 + i;
      const u64* p = (const u64*)hsrc + ((size_t)(((ks - 6) * 4 + kh) * 128 + c.b0 + m)) * 4;
      #pragma unroll
      for (int q = 0; q < 4; q++) xr[i * 4 + q] = aload64(p + q);
    }
    #pragma unroll
    for (int i = 0; i < 2; i++) {
      FR xh, xl; unpack64(&xr[i * 4], xh, xl);
      doKS(WH, WL, wid * 2 + i, lane, xh, xl, acc);
    }
  } else {
    // single ks = 12 + (wid-6) in 12..21 ; kt = wid*4+kh (since ks-6 = wid)
    u64 xr[4];
    const u64* p = (const u64*)hsrc + ((size_t)((wid * 4 + kh) * 128 + c.b0 + m)) * 4;
    #pragma unroll
    for (int q = 0; q < 4; q++) xr[q] = aload64(p + q);
    FR xh, xl; unpack64(xr, xh, xl);
    doKS(WH, WL, 12 + (wid - 6), lane, xh, xl, acc);
  }
  wrplog(c, wid, lane, acc);
  __syncthreads();
  reduce16(c, tid, beffL);
  __syncthreads();
  if (tid < 256) {
    int h = tid >> 4, bl = tid & 15;
    float gi = c.gbuf[(h*4+0)*16+bl], gf = c.gbuf[(h*4+1)*16+bl];
    float gg = c.gbuf[(h*4+2)*16+bl], go = c.gbuf[(h*4+3)*16+bl];
    float cp = rst ? c.cst[512 + tid] : c.cst[tid];
    float cc = sigm(gf) * cp + sigm(gi) * tanhf(gg);
    c.cst[tid] = cc;
    astoreU(c.h1pk + par * HPAR
              + ((size_t)((c.j * 2 + (h >> 3)) * 128 + c.b0 + bl)) * 8 + (h & 7),
            packsplit(sigm(go) * tanhf(cc)));
  }
}

// phase B: decoder L2 (K=1024) + partial logits -> int32 atomicAdd + zero other parity
__device__ __forceinline__ void phaseB(const MC& c, int t, float* __restrict__ db2L) {
  const int tid = threadIdx.x, wid = tid >> 6, lane = tid & 63;
  const int m = lane & 15, kh = lane >> 4;
  const int par = t & 1; const bool rst = (t & 15) == 0;
  const uint* s1 = c.h1pk + par * HPAR;
  const uint* s2 = rst ? c.dh2pk : (c.h2pk + (par ^ 1) * HPAR);
  const uint* WH = c.WBh + (size_t)c.j * 32768;
  const uint* WL = c.WBl + (size_t)c.j * 32768;
  // wave = 2 k-slices: ks = 2*wid, 2*wid+1 (wid<8 -> h1, wid>=8 -> h2)
  u64 xr[8];
  #pragma unroll
  for (int i = 0; i < 2; i++) {
    const int ks = wid * 2 + i;
    const uint* sp = (ks < 16) ? s1 : s2;
    const u64* p = (const u64*)sp + ((size_t)(((ks & 15) * 4 + kh) * 128 + c.b0 + m)) * 4;
    #pragma unroll
    for (int q = 0; q < 4; q++) xr[i * 4 + q] = aload64(p + q);
  }
  f32x4 acc[4] = {{0,0,0,0},{0,0,0,0},{0,0,0,0},{0,0,0,0}};
  #pragma unroll
  for (int i = 0; i < 2; i++) {
    FR xh, xl; unpack64(&xr[i * 4], xh, xl);
    doKS(WH, WL, wid * 2 + i, lane, xh, xl, acc);
  }
  wrplog(c, wid, lane, acc);
  __syncthreads();
  reduce16(c, tid, db2L);
  __syncthreads();
  if (tid < 256) {
    int h = tid >> 4, bl = tid & 15;
    float gi = c.gbuf[(h*4+0)*16+bl], gf = c.gbuf[(h*4+1)*16+bl];
    float gg = c.gbuf[(h*4+2)*16+bl], go = c.gbuf[(h*4+3)*16+bl];
    float cp = rst ? c.cst[768 + tid] : c.cst[256 + tid];
    float cc = sigm(gf) * cp + sigm(gi) * tanhf(gg);
    c.cst[256 + tid] = cc;
    float h2v = sigm(go) * tanhf(cc);
    c.h2s[h * 16 + bl] = h2v;
    astoreU(c.h2pk + par * HPAR
              + ((size_t)((c.j * 2 + (h >> 3)) * 128 + c.b0 + bl)) * 8 + (h & 7),
            packsplit(h2v));
  }
  __syncthreads();
  // partial projection logits over this block's 16-hid slice -> fixed-point atomic add
  const int o = tid & 255, q = tid >> 8;
  if (o < DOn) {
    float wv[16];
    #pragma unroll
    for (int h = 0; h < 16; h++) wv[h] = c.Wp[(size_t)(c.j * 16 + h) * DOn + o];
    #pragma unroll
    for (int rep = 0; rep < 4; rep++) {
      const int bl = q * 4 + rep;
      float s = 0.f;
      #pragma unroll
      for (int h = 0; h < 16; h++) s = fmaf(c.h2s[h * 16 + bl], wv[h], s);
      __hip_atomic_fetch_add(c.accI + par * ACC_PAR + bl * 192 + o,
                             __float2int_rn(s * 1048576.0f),
                             __ATOMIC_RELAXED, __HIP_MEMORY_SCOPE_AGENT);
    }
  }
  // zero the other-parity slice (consumed by phase A earlier this step)
  if (tid < 96)
    astoreU((uint*)(c.accI + (par ^ 1) * ACC_PAR + c.j * 96 + tid), 0u);
}

// ---------------- kernel ----------------
__global__ void __launch_bounds__(NTHR, 1)
hd_kernel(KA A) {
  __shared__ float buf[25088];   // preamble: xs[16384]+part[8704]; main: NTu/plog/gbuf/cst/h2s
  __shared__ float beffL[1024], db2L[1024];
  float* xs = buf;
  float* part = buf + 16384;
  const int bid = blockIdx.x, tid = threadIdx.x;
  const int lane = tid & 63;
  const int kqP = tid >> 6, cgP = lane & 15, bgP = lane >> 4;   // preamble gemm (tid<512)
  const int rP = bid & 31, btP = bid >> 5;
  const int htP = (rP & 7) * 4 + (rP >> 3);
  const int colbaseP = htP * 64, b0P = btP * 16;
  const int pod = bid >> 5;

  // read monotonic barrier base BEFORE any pod activity this launch
  unsigned tgt = __hip_atomic_load(&pod_ctr[pod * 64], __ATOMIC_RELAXED,
                                   __HIP_MEMORY_SCOPE_AGENT) + 32;

  // ---- P-1: z transpose, bias perms, WEp, WA pack, accI zero ----
  {
    const int i0 = bid * NTHR + tid;                 // 0..262143
    if (i0 < 512 * Bn) { int zb = i0 >> 9, zk = i0 & 511; astoreF(A.zT + (size_t)zk * Bn + zb, A.z[i0]); }
    if (i0 < NGn) {
      int hid = i0 >> 2, g = i0 & 3, sc = g * 512 + hid;
      astoreF(A.db1P + i0, A.db1[sc]);
      astoreF(A.db2P + i0, A.db2[sc]);
    }
    if (i0 < 2 * ACC_PAR) astoreU((uint*)(A.accI + i0), 0u);
    for (int i = i0; i < 512 * NGn; i += NBLK * NTHR) {   // WEp[k][cp]
      int k = i >> 11, pc = i & 2047;
      int hid = pc >> 2, g = pc & 3;
      astoreF(A.WEp + i, A.dW1[(size_t)(176 + k) * NGn + g * 512 + hid]);
    }
    for (int i = i0; i < 720896; i += NBLK * NTHR) {      // WA frag planes
      int col = i & 2047, kp = i >> 11, k = kp * 2;
      float w0, w1;
      if (k < 176)      { w0 = A.dW1[(size_t)k * NGn + col];       w1 = A.dW1[(size_t)(k + 1) * NGn + col]; }
      else if (k < 192) { w0 = 0.f; w1 = 0.f; }
      else              { w0 = A.dU1[(size_t)(k - 192) * NGn + col]; w1 = A.dU1[(size_t)(k - 191) * NGn + col]; }
      unsigned short h0, l0, h1, l1; split2(w0, h0, l0); split2(w1, h1, l1);
      int g = col >> 9, hid = col & 511;
      int jj = hid >> 4, cl = (hid & 15) * 4 + g;
      int nt = cl >> 4, n = cl & 15;
      int ks = k >> 5, kr = k & 31, lh = kr >> 3, q = (kr >> 1) & 3;
      int idx = ((jj * 22 + ks) * 4 + nt) * 256 + (lh * 16 + n) * 4 + q;
      astoreU(A.WAh + idx, (uint)h0 | ((uint)h1 << 16));
      astoreU(A.WAl + idx, (uint)l0 | ((uint)l1 << 16));
    }
  }
  gbar();
  // ---- pre0: sT = tanh(z @ Wz + bz) ----
  {
    stageN(xs, A.zT, 512, b0P, tid); __syncthreads();
    if (tid < 512) {
      float acc[16] = {0,0,0,0,0,0,0,0,0,0,0,0,0,0,0,0};
      gemm16<64>(A.Wz, colbaseP, kqP, cgP, bgP, xs, acc);
      pstore(part, kqP, cgP, bgP, acc);
    }
    __syncthreads();
    epi_plain<0>(A.bz, A.sT, colbaseP, b0P, tid, part);
  }
  gbar();
  // ---- pre1: conductor L1 gates ----
  {
    stageN(xs, A.sT, 512, b0P, tid); __syncthreads();
    if (tid < 512) {
      float acc[16] = {0,0,0,0,0,0,0,0,0,0,0,0,0,0,0,0};
      gemm16<64>(A.cU1, colbaseP, kqP, cgP, bgP, xs, acc);
      pstore(part, kqP, cgP, bgP, acc);
    }
    __syncthreads();
    epi_plain<1>(nullptr, A.ggate, colbaseP, b0P, tid, part);
  }
  gbar();
  cond_nl(A.ggate, A.cb1, A.sT + (size_t)512 * Bn, A.h1cT, bid, tid);
  gbar();
  // ---- pre2: conductor L2 gates ----
  {
    stageN(xs, A.h1cT, 512, b0P, tid);
    stageN(xs + 8192, A.sT + (size_t)1024 * Bn, 512, b0P, tid);
    __syncthreads();
    if (tid < 512) {
      float acc[16] = {0,0,0,0,0,0,0,0,0,0,0,0,0,0,0,0};
      gemm16<64>(A.cW2, colbaseP, kqP, cgP, bgP, xs, acc);
      gemm16<64>(A.cU2, colbaseP, kqP, cgP, bgP, xs + 8192, acc);
      pstore(part, kqP, cgP, bgP, acc);
    }
    __syncthreads();
    epi_plain<1>(nullptr, A.ggate, colbaseP, b0P, tid, part);
  }
  gbar();
  cond_nl(A.ggate, A.cb2, A.sT + (size_t)1536 * Bn, A.ceT, bid, tid);
  gbar();
  // ---- pre3: sdT = tanh(ce @ Wcd + bcd); beffP = db1P + ce @ WEp ----
  {
    stageN(xs, A.ceT, 512, b0P, tid); __syncthreads();
    if (tid < 512) {
      float acc[16] = {0,0,0,0,0,0,0,0,0,0,0,0,0,0,0,0};
      gemm16<64>(A.Wcd, colbaseP, kqP, cgP, bgP, xs, acc);
      pstore(part, kqP, cgP, bgP, acc);
    }
    __syncthreads();
    epi_plain<0>(A.bcd, A.sdT, colbaseP, b0P, tid, part);
    __syncthreads();
    if (tid < 512) {
      float acc[16] = {0,0,0,0,0,0,0,0,0,0,0,0,0,0,0,0};
      gemm16<64>(A.WEp, colbaseP, kqP, cgP, bgP, xs, acc);
      pstore(part, kqP, cgP, bgP, acc);
    }
    __syncthreads();
    epi_plain<1>(A.db1P, A.beffP, colbaseP, b0P, tid, part);
  }
  gbar();
  // ---- P4: WB pack (overwrites WEp) + dh packs (new [kt][b][8] layout) ----
  {
    const int i0 = bid * NTHR + tid;
    for (int i = i0; i < 1048576; i += NBLK * NTHR) {
      int col = i & 2047, kp = i >> 11, k = kp * 2;
      float w0, w1;
      if (k < 512) { w0 = A.dW2[(size_t)k * NGn + col];         w1 = A.dW2[(size_t)(k + 1) * NGn + col]; }
      else         { w0 = A.dU2[(size_t)(k - 512) * NGn + col]; w1 = A.dU2[(size_t)(k - 511) * NGn + col]; }
      unsigned short h0, l0, h1, l1; split2(w0, h0, l0); split2(w1, h1, l1);
      int g = col >> 9, hid = col & 511;
      int jj = hid >> 4, cl = (hid & 15) * 4 + g;
      int nt = cl >> 4, n = cl & 15;
      int ks = k >> 5, kr = k & 31, lh = kr >> 3, q = (kr >> 1) & 3;
      int idx = ((jj * 32 + ks) * 4 + nt) * 256 + (lh * 16 + n) * 4 + q;
      astoreU(A.WBh + idx, (uint)h0 | ((uint)h1 << 16));
      astoreU(A.WBl + idx, (uint)l0 | ((uint)l1 << 16));
    }
    if (i0 < 512 * Bn) {
      int hid = i0 >> 7, b = i0 & 127;
      astoreU(A.dh1pk + ((size_t)((hid >> 3) * 128 + b)) * 8 + (hid & 7),
              packsplit(aloadF(A.sdT + (size_t)hid * Bn + b)));
      astoreU(A.dh2pk + ((size_t)((hid >> 3) * 128 + b)) * 8 + (hid & 7),
              packsplit(aloadF(A.sdT + (size_t)(1024 + hid) * Bn + b)));
    }
  }
  gbar();

  // ---- main loop ----
  MC c;
  c.WAh = A.WAh; c.WAl = A.WAl; c.WBh = A.WBh; c.WBl = A.WBl;
  c.dh1pk = A.dh1pk; c.dh2pk = A.dh2pk;
  c.h1pk = A.h1pk; c.h2pk = A.h2pk;
  c.beffP = A.beffP; c.db2P = A.db2P; c.Wp = A.Wp; c.bp = A.bp; c.out = A.out;
  c.accI = A.accI + pod * 3072;
  c.NTu = (uint*)buf;            // 3072 uints ([kt 24][16][8])
  c.plog = buf + 3072;           // 64 slots x 4 r x 68 = 17408
  c.gbuf = buf + 20480;          // 1024
  c.cst  = buf + 21504;          // 1024
  c.h2s  = buf + 22528;          // 256
  c.j = bid & 31;
  c.b0 = pod * 16;
  if (tid < 256) {
    int h = tid >> 4, bl = tid & 15;
    c.cst[512 + tid] = aloadF(A.sdT + (size_t)(512 + c.j * 16 + h) * Bn + c.b0 + bl);
    c.cst[768 + tid] = aloadF(A.sdT + (size_t)(1536 + c.j * 16 + h) * Bn + c.b0 + bl);
  }
  // LDS-resident per-block bias tiles (cut per-step L2/L3 reads)
  {
    int cl = tid >> 4, bl = tid & 15;
    beffL[tid] = aloadF(A.beffP + (size_t)(c.j * 64 + cl) * Bn + c.b0 + bl);
    db2L[tid] = A.db2P[c.j * 64 + cl];
  }
  for (int i = tid; i < 3072; i += NTHR) c.NTu[i] = 0u;   // note(0) = 0 + pad rows
  __syncthreads();

  for (int t = 0; t < TTn; t++) {
    phaseA(c, t, true, beffL);
    pbar2(pod, tgt);
    phaseB(c, t, db2L);
    pbar2(pod, tgt);
  }
  phaseA(c, TTn, false, beffL);   // final softmax -> out[255]
}

extern "C" void kernel_launch(void* const* d_in, const int* in_sizes, int n_in,
                              void* d_out, int out_size, void* d_ws, size_t ws_size,
                              hipStream_t stream) {
  (void)in_sizes; (void)n_in; (void)out_size; (void)ws_size;
  KA a;
  a.z   = (const float*)d_in[0];
  a.Wz  = (const float*)d_in[3];  a.bz  = (const float*)d_in[4];
  // d_in[5] = cond_W1 unused (conductor input x0 == 0)
  a.cU1 = (const float*)d_in[6];  a.cb1 = (const float*)d_in[7];
  a.cW2 = (const float*)d_in[8];  a.cU2 = (const float*)d_in[9];  a.cb2 = (const float*)d_in[10];
  a.Wcd = (const float*)d_in[11]; a.bcd = (const float*)d_in[12];
  a.dW1 = (const float*)d_in[13]; a.dU1 = (const float*)d_in[14]; a.db1 = (const float*)d_in[15];
  a.dW2 = (const float*)d_in[16]; a.dU2 = (const float*)d_in[17]; a.db2 = (const float*)d_in[18];
  a.Wp  = (const float*)d_in[19]; a.bp  = (const float*)d_in[20];

  float* ws = (float*)d_ws;
  size_t off = 0;
  a.zT    = ws + off; off += (size_t)512  * Bn;
  a.sT    = ws + off; off += (size_t)NGn  * Bn;
  a.ggate = ws + off; off += (size_t)NGn  * Bn;
  a.h1cT  = ws + off; off += (size_t)512  * Bn;
  a.ceT   = ws + off; off += (size_t)512  * Bn;
  a.sdT   = ws + off; off += (size_t)NGn  * Bn;       // dh1|dc1|dh2|dc2
  a.beffP = ws + off; off += (size_t)NGn  * Bn;       // [cp][b]
  a.db1P  = ws + off; off += (size_t)NGn;
  a.db2P  = ws + off; off += (size_t)NGn;
  a.WEp   = ws + off; off += (size_t)512 * NGn;       // aliased by WBh in P4
  a.WBh   = (uint*)a.WEp;
  a.WBl   = (uint*)(ws + off); off += (size_t)1048576;
  a.WAh   = (uint*)(ws + off); off += (size_t)720896;
  a.WAl   = (uint*)(ws + off); off += (size_t)720896;
  a.h1pk  = (uint*)(ws + off); off += (size_t)2 * HPAR;
  a.h2pk  = (uint*)(ws + off); off += (size_t)2 * HPAR;
  a.dh1pk = (uint*)(ws + off); off += (size_t)HPAR;
  a.dh2pk = (uint*)(ws + off); off += (size_t)HPAR;
  a.accI  = (int*)(ws + off);  off += (size_t)2 * ACC_PAR;
  a.out   = (float*)d_out;

  hd_kernel<<<dim3(NBLK), dim3(NTHR), 0, stream>>>(a);
}

// Round 13
// 6941.614 us; speedup vs baseline: 1.3545x; 1.0309x over previous
//
#include <hip/hip_runtime.h>
#include <hip/hip_bf16.h>
#include <math.h>

// ---- dims ----
#define Bn    128
#define NGn   2048
#define TTn   256
#define DOn   176
#define NBLK  256
#define NTHR  1024
#define HPAR  65536          // 512*128 uints per parity, layout [k/8][128 b][8]
#define ACC_PAR 24576        // ints per parity in accI (8 pods x 16 b x 192)

typedef unsigned int uint;
typedef unsigned long long u64;
using f32x4 = __attribute__((ext_vector_type(4))) float;
using s16x8 = __attribute__((ext_vector_type(8))) short;
union FR { uint u[4]; s16x8 s; };

struct KA {
  const float *z,*Wz,*bz,*cU1,*cb1,*cW2,*cU2,*cb2,*Wcd,*bcd;
  const float *dW1,*dU1,*db1,*dW2,*dU2,*db2,*Wp,*bp;
  float *zT,*sT,*ggate,*h1cT,*ceT,*sdT,*beffP,*db1P,*db2P,*WEp,*out;
  uint *WAh,*WAl,*WBh,*WBl,*h1pk,*h2pk,*dh1pk,*dh2pk;
  int  *accI;
};

// ---- barrier state ----
__device__ unsigned g_cnt_l1[16 * 32];
__device__ unsigned g_cnt;
__device__ unsigned g_gen;
__device__ unsigned pod_slot[8 * 32 * 32];   // per-block monotonic flag, 128B apart

__device__ __forceinline__ float sigm(float x) { return 1.0f / (1.0f + __expf(-x)); }

__device__ __forceinline__ float aloadF(const float* p) {
  return __hip_atomic_load(p, __ATOMIC_RELAXED, __HIP_MEMORY_SCOPE_AGENT);
}
__device__ __forceinline__ void astoreF(float* p, float v) {
  __hip_atomic_store(p, v, __ATOMIC_RELAXED, __HIP_MEMORY_SCOPE_AGENT);
}
__device__ __forceinline__ uint aloadU(const uint* p) {
  return __hip_atomic_load(p, __ATOMIC_RELAXED, __HIP_MEMORY_SCOPE_AGENT);
}
__device__ __forceinline__ void astoreU(uint* p, uint v) {
  __hip_atomic_store(p, v, __ATOMIC_RELAXED, __HIP_MEMORY_SCOPE_AGENT);
}
__device__ __forceinline__ int aloadI(const int* p) {
  return __hip_atomic_load(p, __ATOMIC_RELAXED, __HIP_MEMORY_SCOPE_AGENT);
}
__device__ __forceinline__ u64 aload64(const u64* p) {
  return __hip_atomic_load(p, __ATOMIC_RELAXED, __HIP_MEMORY_SCOPE_AGENT);
}

// split v = hi + lo (both bf16, RNE)
__device__ __forceinline__ void split2(float v, unsigned short& h, unsigned short& l) {
  __hip_bfloat16 bh = __float2bfloat16(v);
  float hf = __bfloat162float(bh);
  __hip_bfloat16 bl = __float2bfloat16(v - hf);
  h = *(unsigned short*)&bh; l = *(unsigned short*)&bl;
}
__device__ __forceinline__ uint packsplit(float v) {
  unsigned short h, l; split2(v, h, l);
  return (uint)h | ((uint)l << 16);
}

// global barrier (preamble only)
__device__ __forceinline__ void gbar() {
  __syncthreads();
  if (threadIdx.x == 0) {
    asm volatile("s_waitcnt vmcnt(0)" ::: "memory");
    unsigned g0 = __hip_atomic_load(&g_gen, __ATOMIC_RELAXED, __HIP_MEMORY_SCOPE_AGENT);
    unsigned p1 = __hip_atomic_fetch_add(&g_cnt_l1[(blockIdx.x >> 4) * 32], 1u,
                                         __ATOMIC_RELAXED, __HIP_MEMORY_SCOPE_AGENT);
    if (p1 == 15u) {
      unsigned p2 = __hip_atomic_fetch_add(&g_cnt, 1u, __ATOMIC_RELAXED, __HIP_MEMORY_SCOPE_AGENT);
      if (p2 == 15u) {
        #pragma unroll
        for (int i = 0; i < 16; i++)
          __hip_atomic_store(&g_cnt_l1[i * 32], 0u, __ATOMIC_RELAXED, __HIP_MEMORY_SCOPE_AGENT);
        __hip_atomic_store(&g_cnt, 0u, __ATOMIC_RELAXED, __HIP_MEMORY_SCOPE_AGENT);
        asm volatile("s_waitcnt vmcnt(0)" ::: "memory");
        __hip_atomic_fetch_add(&g_gen, 1u, __ATOMIC_RELAXED, __HIP_MEMORY_SCOPE_AGENT);
      }
    }
    while (__hip_atomic_load(&g_gen, __ATOMIC_RELAXED, __HIP_MEMORY_SCOPE_AGENT) == g0)
      __builtin_amdgcn_s_sleep(1);
  }
  __syncthreads();
}

// slot-flag pod barrier: each block WRITES its own 128B-spaced flag (no RMW
// serialization); wave-0 lanes 0..31 each poll one block's flag. Monotonic,
// no reset; base read per-launch from own slot (all slots equal at launch start).
__device__ __forceinline__ void pbarS(int pod, int j, unsigned& tgt) {
  __syncthreads();
  if (threadIdx.x < 32) {
    if (threadIdx.x == 0) {
      asm volatile("s_waitcnt vmcnt(0)" ::: "memory");   // data visible before flag
      astoreU(&pod_slot[(pod * 32 + j) * 32], tgt);
    }
    const uint* sl = &pod_slot[(pod * 32 + (int)threadIdx.x) * 32];
    while ((int)(aloadU(sl) - tgt) < 0) { }
  }
  __syncthreads();
  tgt += 1;
}

// ---------------- preamble f32 helpers (rounds 4-11 proven) ----------------
__device__ __forceinline__ void stageN(float* __restrict__ xs, const float* __restrict__ X,
                                       int nrows, int b0, int tid) {
  for (int i = tid; i < nrows * 16; i += NTHR)
    xs[i] = aloadF(X + (size_t)(i >> 4) * Bn + b0 + (i & 15));
}

template<int KC>
__device__ __forceinline__ void gemm16(const float* __restrict__ Wb, int colbase,
                                       int kq, int cg, int bg,
                                       const float* __restrict__ xsrc, float acc[16]) {
  const float* wp = Wb + (size_t)(kq * KC) * NGn + colbase + cg * 4;
  const float* xp = xsrc + (kq * KC) * 16 + bg * 4;
  #pragma unroll 2
  for (int kk = 0; kk < KC; kk++) {
    const float4 w4 = *(const float4*)(wp);
    const float4 x4 = *(const float4*)(xp);
    acc[0]  = fmaf(w4.x, x4.x, acc[0]);  acc[1]  = fmaf(w4.x, x4.y, acc[1]);
    acc[2]  = fmaf(w4.x, x4.z, acc[2]);  acc[3]  = fmaf(w4.x, x4.w, acc[3]);
    acc[4]  = fmaf(w4.y, x4.x, acc[4]);  acc[5]  = fmaf(w4.y, x4.y, acc[5]);
    acc[6]  = fmaf(w4.y, x4.z, acc[6]);  acc[7]  = fmaf(w4.y, x4.w, acc[7]);
    acc[8]  = fmaf(w4.z, x4.x, acc[8]);  acc[9]  = fmaf(w4.z, x4.y, acc[9]);
    acc[10] = fmaf(w4.z, x4.z, acc[10]); acc[11] = fmaf(w4.z, x4.w, acc[11]);
    acc[12] = fmaf(w4.w, x4.x, acc[12]); acc[13] = fmaf(w4.w, x4.y, acc[13]);
    acc[14] = fmaf(w4.w, x4.z, acc[14]); acc[15] = fmaf(w4.w, x4.w, acc[15]);
    wp += NGn; xp += 16;
  }
}

__device__ __forceinline__ void pstore(float* __restrict__ part, int kq, int cg, int bg,
                                       const float acc[16]) {
  #pragma unroll
  for (int c = 0; c < 4; c++) {
    float* p = part + (size_t)(kq * 64 + cg * 4 + c) * 17 + bg * 4;
    *(float4*)p = make_float4(acc[c*4], acc[c*4+1], acc[c*4+2], acc[c*4+3]);
  }
}

template<int MODE>
__device__ __forceinline__ void epi_plain(const float* bias, float* out,
                                          int colbase, int b0, int tid,
                                          const float* __restrict__ part) {
  int cl = tid >> 4, bl = tid & 15;
  float s = 0.0f;
  #pragma unroll
  for (int w = 0; w < 8; w++) s += part[(w * 64 + cl) * 17 + bl];
  if (bias) s += bias[colbase + cl];
  if (MODE == 0) s = tanhf(s);
  astoreF(out + (size_t)(colbase + cl) * Bn + b0 + bl, s);
}

__device__ __forceinline__ void cond_nl(const float* gb, const float* cbias,
                                        const float* cin, float* hout, int bid, int tid) {
  int i = bid * NTHR + tid;
  if (i < 512 * Bn) {
    int hid = i >> 7, b = i & 127;
    float gi = aloadF(gb + (size_t)hid * Bn + b)            + cbias[hid];
    float gf = aloadF(gb + (size_t)(512 + hid) * Bn + b)    + cbias[512 + hid];
    float gg = aloadF(gb + (size_t)(1024 + hid) * Bn + b)   + cbias[1024 + hid];
    float go = aloadF(gb + (size_t)(1536 + hid) * Bn + b)   + cbias[1536 + hid];
    float cprev = aloadF(cin + (size_t)hid * Bn + b);
    float c = sigm(gf) * cprev + sigm(gi) * tanhf(gg);
    astoreF(hout + (size_t)hid * Bn + b, sigm(go) * tanhf(c));
  }
}

// ---------------- main-loop MFMA machinery ----------------
// frag maps (rounds 5-11 verified): A(x): m=lane&15, k=(lane>>4)*8+e.
// B(w): n=lane&15, k=(lane>>4)*8+e. D: n=lane&15, m=(lane>>4)*4+reg.
__device__ __forceinline__ void unpack64(const u64* d, FR& xh, FR& xl) {
  #pragma unroll
  for (int q = 0; q < 4; q++) {
    uint lo = (uint)d[q], hi = (uint)(d[q] >> 32);
    xh.u[q] = (lo & 0xffffu) | (hi << 16);
    xl.u[q] = (lo >> 16) | (hi & 0xffff0000u);
  }
}
__device__ __forceinline__ void unpackU8(uint4 a, uint4 b, FR& xh, FR& xl) {
  xh.u[0] = (a.x & 0xffffu) | (a.y << 16); xl.u[0] = (a.x >> 16) | (a.y & 0xffff0000u);
  xh.u[1] = (a.z & 0xffffu) | (a.w << 16); xl.u[1] = (a.z >> 16) | (a.w & 0xffff0000u);
  xh.u[2] = (b.x & 0xffffu) | (b.y << 16); xl.u[2] = (b.x >> 16) | (b.y & 0xffff0000u);
  xh.u[3] = (b.z & 0xffffu) | (b.w << 16); xl.u[3] = (b.z >> 16) | (b.w & 0xffff0000u);
}

struct MC {
  const uint *WAh,*WAl,*WBh,*WBl,*dh1pk,*dh2pk;
  uint *h1pk,*h2pk;
  const float *beffP,*db2P,*Wp,*bp;
  int *accI;
  float *out;
  uint *NTu;                      // LDS note: [kt 0..23][b 16][8]
  float *plog,*gbuf,*cst,*h2s;    // LDS
  int j, b0;
};

#define MFMA3(ACC, XH, XL, WH, WL)                                            \
  ACC = __builtin_amdgcn_mfma_f32_16x16x32_bf16(XH.s, WH.s, ACC, 0, 0, 0);    \
  ACC = __builtin_amdgcn_mfma_f32_16x16x32_bf16(XL.s, WH.s, ACC, 0, 0, 0);    \
  ACC = __builtin_amdgcn_mfma_f32_16x16x32_bf16(XH.s, WL.s, ACC, 0, 0, 0);

// process one ks: all 4 nt tiles into acc[4]
__device__ __forceinline__ void doKS(const uint* WH, const uint* WL, int ks, int lane,
                                     const FR& xh, const FR& xl, f32x4 acc[4]) {
  #pragma unroll
  for (int nt = 0; nt < 4; nt++) {
    FR wh, wl;
    *(uint4*)wh.u = *(const uint4*)(WH + (ks * 4 + nt) * 256 + lane * 4);
    *(uint4*)wl.u = *(const uint4*)(WL + (ks * 4 + nt) * 256 + lane * 4);
    MFMA3(acc[nt], xh, xl, wh, wl)
  }
}

__device__ __forceinline__ void wrplog(const MC& c, int wid, int lane, const f32x4 acc[4]) {
  #pragma unroll
  for (int nt = 0; nt < 4; nt++)
    #pragma unroll
    for (int r = 0; r < 4; r++)
      c.plog[((wid * 4 + nt) * 4 + r) * 68 + lane] = acc[nt][r];
}

// 16-term reduce into gbuf + bias
__device__ __forceinline__ void reduce16(const MC& c, int tid, const float* biasv) {
  int cl = tid >> 4, bl = tid & 15;
  float s = 0.f;
  #pragma unroll
  for (int k2 = 0; k2 < 16; k2++)
    s += c.plog[((k2 * 4 + (cl >> 4)) * 4 + (bl & 3)) * 68 + (bl >> 2) * 16 + (cl & 15)];
  c.gbuf[cl * 16 + bl] = s + biasv[cl * 16 + bl];
}

// softmax body from prefetched accI ints (wave wv = batch); writes NTu + out(t-1)
__device__ __forceinline__ void smBody(const MC& c, int t, int wv, int lane,
                                       int ai0, int ai1, int ai2) {
  float lg[3], pv[3];
  const int o0 = lane, o1 = lane + 64, o2 = lane + 128;
  lg[0] = (o0 < DOn) ? (float)ai0 * (1.0f / 1048576.0f) + c.bp[o0] : -1e30f;
  lg[1] = (o1 < DOn) ? (float)ai1 * (1.0f / 1048576.0f) + c.bp[o1] : -1e30f;
  lg[2] = (o2 < DOn) ? (float)ai2 * (1.0f / 1048576.0f) + c.bp[o2] : -1e30f;
  float mx = fmaxf(fmaxf(lg[0], lg[1]), lg[2]);
  #pragma unroll
  for (int d = 1; d < 64; d <<= 1) mx = fmaxf(mx, __shfl_xor(mx, d));
  float sum = 0.f;
  #pragma unroll
  for (int rep = 0; rep < 3; rep++) {
    int o = lane + rep * 64;
    pv[rep] = (o < DOn) ? __expf(lg[rep] - mx) : 0.f;
    sum += pv[rep];
  }
  #pragma unroll
  for (int d = 1; d < 64; d <<= 1) sum += __shfl_xor(sum, d);
  const float inv = 1.0f / sum;
  #pragma unroll
  for (int rep = 0; rep < 3; rep++) {
    int o = lane + rep * 64;
    float p = pv[rep] * inv;
    c.NTu[((o >> 3) * 16 + wv) * 8 + (o & 7)] = (o < DOn) ? packsplit(p) : 0u;
    if (c.j < 16 && wv == c.j && o < DOn)
      c.out[((size_t)(c.b0 + c.j) * TTn + (t - 1)) * DOn + o] = p;
  }
}

// one decoder step: [softmax front + L1] pbar [L2 + partial logits] pbar
__device__ __forceinline__ void stepFn(const MC& c, int t, const float* beffL,
                                       const float* db2L, int pod, unsigned& tgt) {
  const int tid = threadIdx.x, wid = tid >> 6, lane = tid & 63;
  const int m = lane & 15, kh = lane >> 4;
  const int par = t & 1; const bool rst = (t & 15) == 0;

  // ==== top-of-step prefetch (plain agent loads; hide under softmax/L1/barrier) ====
  int ai0 = 0, ai1 = 0, ai2 = 0;
  if (t > 0) {
    const int* ai = c.accI + ((par ^ 1) * ACC_PAR) + wid * 192 + lane;
    ai0 = aloadI(ai); ai1 = aloadI(ai + 64); ai2 = aloadI(ai + 128);
  }
  u64 xa[8];
  const uint* hsrcA = rst ? c.dh1pk : (c.h1pk + (par ^ 1) * HPAR);
  if (wid >= 3 && wid < 6) {
    #pragma unroll
    for (int i = 0; i < 2; i++) {
      const u64* p = (const u64*)hsrcA
                   + ((size_t)(((wid * 2 - 6 + i) * 4 + kh) * 128 + c.b0 + m)) * 4;
      #pragma unroll
      for (int q = 0; q < 4; q++) xa[i * 4 + q] = aload64(p + q);
    }
  } else if (wid >= 6) {
    const u64* p = (const u64*)hsrcA + ((size_t)((wid * 4 + kh) * 128 + c.b0 + m)) * 4;
    #pragma unroll
    for (int q = 0; q < 4; q++) xa[q] = aload64(p + q);
  }
  u64 xb[8];
  if (wid >= 8) {
    const uint* s2 = rst ? c.dh2pk : (c.h2pk + (par ^ 1) * HPAR);
    #pragma unroll
    for (int i = 0; i < 2; i++) {
      const int ks = wid * 2 + i;             // 16..31
      const u64* p = (const u64*)s2
                   + ((size_t)(((ks & 15) * 4 + kh) * 128 + c.b0 + m)) * 4;
      #pragma unroll
      for (int q = 0; q < 4; q++) xb[i * 4 + q] = aload64(p + q);
    }
  }

  // ==== softmax front (t>0) ====
  if (t > 0) smBody(c, t, wid, lane, ai0, ai1, ai2);
  __syncthreads();

  // ==== decoder L1 ====
  {
    const uint* WH = c.WAh + (size_t)c.j * 22528;
    const uint* WL = c.WAl + (size_t)c.j * 22528;
    f32x4 acc[4] = {{0,0,0,0},{0,0,0,0},{0,0,0,0},{0,0,0,0}};
    if (wid < 3) {
      #pragma unroll
      for (int i = 0; i < 2; i++) {
        const int ks = wid * 2 + i;
        const uint* p = c.NTu + ((ks * 4 + kh) * 16 + m) * 8;
        uint4 a = *(const uint4*)p, b = *(const uint4*)(p + 4);
        FR xh, xl; unpackU8(a, b, xh, xl);
        doKS(WH, WL, ks, lane, xh, xl, acc);
      }
    } else if (wid < 6) {
      FR xh, xl;
      unpack64(&xa[0], xh, xl); doKS(WH, WL, wid * 2, lane, xh, xl, acc);
      unpack64(&xa[4], xh, xl); doKS(WH, WL, wid * 2 + 1, lane, xh, xl, acc);
    } else {
      FR xh, xl; unpack64(&xa[0], xh, xl);
      doKS(WH, WL, 12 + (wid - 6), lane, xh, xl, acc);
    }
    wrplog(c, wid, lane, acc);
  }
  __syncthreads();
  reduce16(c, tid, beffL);
  __syncthreads();
  if (tid < 256) {
    int h = tid >> 4, bl = tid & 15;
    float gi = c.gbuf[(h*4+0)*16+bl], gf = c.gbuf[(h*4+1)*16+bl];
    float gg = c.gbuf[(h*4+2)*16+bl], go = c.gbuf[(h*4+3)*16+bl];
    float cp = rst ? c.cst[512 + tid] : c.cst[tid];
    float cc = sigm(gf) * cp + sigm(gi) * tanhf(gg);
    c.cst[tid] = cc;
    astoreU(c.h1pk + par * HPAR
              + ((size_t)((c.j * 2 + (h >> 3)) * 128 + c.b0 + bl)) * 8 + (h & 7),
            packsplit(sigm(go) * tanhf(cc)));
  }
  pbarS(pod, c.j, tgt);

  // ==== decoder L2 ====
  if (wid < 8) {
    const uint* s1 = c.h1pk + par * HPAR;
    #pragma unroll
    for (int i = 0; i < 2; i++) {
      const int ks = wid * 2 + i;
      const u64* p = (const u64*)s1 + ((size_t)((ks * 4 + kh) * 128 + c.b0 + m)) * 4;
      #pragma unroll
      for (int q = 0; q < 4; q++) xb[i * 4 + q] = aload64(p + q);
    }
  }
  {
    const uint* WH = c.WBh + (size_t)c.j * 32768;
    const uint* WL = c.WBl + (size_t)c.j * 32768;
    f32x4 acc[4] = {{0,0,0,0},{0,0,0,0},{0,0,0,0},{0,0,0,0}};
    FR xh, xl;
    unpack64(&xb[0], xh, xl); doKS(WH, WL, wid * 2, lane, xh, xl, acc);
    unpack64(&xb[4], xh, xl); doKS(WH, WL, wid * 2 + 1, lane, xh, xl, acc);
    wrplog(c, wid, lane, acc);
  }
  __syncthreads();
  reduce16(c, tid, db2L);
  __syncthreads();
  if (tid < 256) {
    int h = tid >> 4, bl = tid & 15;
    float gi = c.gbuf[(h*4+0)*16+bl], gf = c.gbuf[(h*4+1)*16+bl];
    float gg = c.gbuf[(h*4+2)*16+bl], go = c.gbuf[(h*4+3)*16+bl];
    float cp = rst ? c.cst[768 + tid] : c.cst[256 + tid];
    float cc = sigm(gf) * cp + sigm(gi) * tanhf(gg);
    c.cst[256 + tid] = cc;
    float h2v = sigm(go) * tanhf(cc);
    c.h2s[h * 16 + bl] = h2v;
    astoreU(c.h2pk + par * HPAR
              + ((size_t)((c.j * 2 + (h >> 3)) * 128 + c.b0 + bl)) * 8 + (h & 7),
            packsplit(h2v));
  }
  __syncthreads();
  // partial projection logits -> fixed-point atomic add + zero other parity
  {
    const int o = tid & 255, q = tid >> 8;
    if (o < DOn) {
      float wv[16];
      #pragma unroll
      for (int h = 0; h < 16; h++) wv[h] = c.Wp[(size_t)(c.j * 16 + h) * DOn + o];
      #pragma unroll
      for (int rep = 0; rep < 4; rep++) {
        const int bl = q * 4 + rep;
        float s = 0.f;
        #pragma unroll
        for (int h = 0; h < 16; h++) s = fmaf(c.h2s[h * 16 + bl], wv[h], s);
        __hip_atomic_fetch_add(c.accI + par * ACC_PAR + bl * 192 + o,
                               __float2int_rn(s * 1048576.0f),
                               __ATOMIC_RELAXED, __HIP_MEMORY_SCOPE_AGENT);
      }
    }
    if (tid < 96)
      astoreU((uint*)(c.accI + (par ^ 1) * ACC_PAR + c.j * 96 + tid), 0u);
  }
  pbarS(pod, c.j, tgt);
}

// final softmax (t = TTn) -> out[255]
__device__ __forceinline__ void smTail(const MC& c, int t) {
  const int tid = threadIdx.x, wid = tid >> 6, lane = tid & 63;
  const int par = t & 1;
  const int* ai = c.accI + ((par ^ 1) * ACC_PAR) + wid * 192 + lane;
  smBody(c, t, wid, lane, aloadI(ai), aloadI(ai + 64), aloadI(ai + 128));
}

// ---------------- kernel ----------------
__global__ void __launch_bounds__(NTHR, 1)
hd_kernel(KA A) {
  __shared__ float buf[25088];   // preamble: xs[16384]+part[8704]; main: NTu/plog/gbuf/cst/h2s
  __shared__ float beffL[1024], db2L[1024];
  float* xs = buf;
  float* part = buf + 16384;
  const int bid = blockIdx.x, tid = threadIdx.x;
  const int lane = tid & 63;
  const int kqP = tid >> 6, cgP = lane & 15, bgP = lane >> 4;   // preamble gemm (tid<512)
  const int rP = bid & 31, btP = bid >> 5;
  const int htP = (rP & 7) * 4 + (rP >> 3);
  const int colbaseP = htP * 64, b0P = btP * 16;
  const int pod = bid >> 5;

  // monotonic slot-barrier base: read OWN slot before any arrival this launch
  unsigned tgt = aloadU(&pod_slot[(pod * 32 + (bid & 31)) * 32]) + 1;

  // ---- P-1: z transpose, bias perms, WEp, WA pack, accI zero ----
  {
    const int i0 = bid * NTHR + tid;                 // 0..262143
    if (i0 < 512 * Bn) { int zb = i0 >> 9, zk = i0 & 511; astoreF(A.zT + (size_t)zk * Bn + zb, A.z[i0]); }
    if (i0 < NGn) {
      int hid = i0 >> 2, g = i0 & 3, sc = g * 512 + hid;
      astoreF(A.db1P + i0, A.db1[sc]);
      astoreF(A.db2P + i0, A.db2[sc]);
    }
    if (i0 < 2 * ACC_PAR) astoreU((uint*)(A.accI + i0), 0u);
    for (int i = i0; i < 512 * NGn; i += NBLK * NTHR) {   // WEp[k][cp]
      int k = i >> 11, pc = i & 2047;
      int hid = pc >> 2, g = pc & 3;
      astoreF(A.WEp + i, A.dW1[(size_t)(176 + k) * NGn + g * 512 + hid]);
    }
    for (int i = i0; i < 720896; i += NBLK * NTHR) {      // WA frag planes
      int col = i & 2047, kp = i >> 11, k = kp * 2;
      float w0, w1;
      if (k < 176)      { w0 = A.dW1[(size_t)k * NGn + col];       w1 = A.dW1[(size_t)(k + 1) * NGn + col]; }
      else if (k < 192) { w0 = 0.f; w1 = 0.f; }
      else              { w0 = A.dU1[(size_t)(k - 192) * NGn + col]; w1 = A.dU1[(size_t)(k - 191) * NGn + col]; }
      unsigned short h0, l0, h1, l1; split2(w0, h0, l0); split2(w1, h1, l1);
      int g = col >> 9, hid = col & 511;
      int jj = hid >> 4, cl = (hid & 15) * 4 + g;
      int nt = cl >> 4, n = cl & 15;
      int ks = k >> 5, kr = k & 31, lh = kr >> 3, q = (kr >> 1) & 3;
      int idx = ((jj * 22 + ks) * 4 + nt) * 256 + (lh * 16 + n) * 4 + q;
      astoreU(A.WAh + idx, (uint)h0 | ((uint)h1 << 16));
      astoreU(A.WAl + idx, (uint)l0 | ((uint)l1 << 16));
    }
  }
  gbar();
  // ---- pre0: sT = tanh(z @ Wz + bz) ----
  {
    stageN(xs, A.zT, 512, b0P, tid); __syncthreads();
    if (tid < 512) {
      float acc[16] = {0,0,0,0,0,0,0,0,0,0,0,0,0,0,0,0};
      gemm16<64>(A.Wz, colbaseP, kqP, cgP, bgP, xs, acc);
      pstore(part, kqP, cgP, bgP, acc);
    }
    __syncthreads();
    epi_plain<0>(A.bz, A.sT, colbaseP, b0P, tid, part);
  }
  gbar();
  // ---- pre1: conductor L1 gates ----
  {
    stageN(xs, A.sT, 512, b0P, tid); __syncthreads();
    if (tid < 512) {
      float acc[16] = {0,0,0,0,0,0,0,0,0,0,0,0,0,0,0,0};
      gemm16<64>(A.cU1, colbaseP, kqP, cgP, bgP, xs, acc);
      pstore(part, kqP, cgP, bgP, acc);
    }
    __syncthreads();
    epi_plain<1>(nullptr, A.ggate, colbaseP, b0P, tid, part);
  }
  gbar();
  cond_nl(A.ggate, A.cb1, A.sT + (size_t)512 * Bn, A.h1cT, bid, tid);
  gbar();
  // ---- pre2: conductor L2 gates ----
  {
    stageN(xs, A.h1cT, 512, b0P, tid);
    stageN(xs + 8192, A.sT + (size_t)1024 * Bn, 512, b0P, tid);
    __syncthreads();
    if (tid < 512) {
      float acc[16] = {0,0,0,0,0,0,0,0,0,0,0,0,0,0,0,0};
      gemm16<64>(A.cW2, colbaseP, kqP, cgP, bgP, xs, acc);
      gemm16<64>(A.cU2, colbaseP, kqP, cgP, bgP, xs + 8192, acc);
      pstore(part, kqP, cgP, bgP, acc);
    }
    __syncthreads();
    epi_plain<1>(nullptr, A.ggate, colbaseP, b0P, tid, part);
  }
  gbar();
  cond_nl(A.ggate, A.cb2, A.sT + (size_t)1536 * Bn, A.ceT, bid, tid);
  gbar();
  // ---- pre3: sdT = tanh(ce @ Wcd + bcd); beffP = db1P + ce @ WEp ----
  {
    stageN(xs, A.ceT, 512, b0P, tid); __syncthreads();
    if (tid < 512) {
      float acc[16] = {0,0,0,0,0,0,0,0,0,0,0,0,0,0,0,0};
      gemm16<64>(A.Wcd, colbaseP, kqP, cgP, bgP, xs, acc);
      pstore(part, kqP, cgP, bgP, acc);
    }
    __syncthreads();
    epi_plain<0>(A.bcd, A.sdT, colbaseP, b0P, tid, part);
    __syncthreads();
    if (tid < 512) {
      float acc[16] = {0,0,0,0,0,0,0,0,0,0,0,0,0,0,0,0};
      gemm16<64>(A.WEp, colbaseP, kqP, cgP, bgP, xs, acc);
      pstore(part, kqP, cgP, bgP, acc);
    }
    __syncthreads();
    epi_plain<1>(A.db1P, A.beffP, colbaseP, b0P, tid, part);
  }
  gbar();
  // ---- P4: WB pack (overwrites WEp) + dh packs ([kt][b][8] layout) ----
  {
    const int i0 = bid * NTHR + tid;
    for (int i = i0; i < 1048576; i += NBLK * NTHR) {
      int col = i & 2047, kp = i >> 11, k = kp * 2;
      float w0, w1;
      if (k < 512) { w0 = A.dW2[(size_t)k * NGn + col];         w1 = A.dW2[(size_t)(k + 1) * NGn + col]; }
      else         { w0 = A.dU2[(size_t)(k - 512) * NGn + col]; w1 = A.dU2[(size_t)(k - 511) * NGn + col]; }
      unsigned short h0, l0, h1, l1; split2(w0, h0, l0); split2(w1, h1, l1);
      int g = col >> 9, hid = col & 511;
      int jj = hid >> 4, cl = (hid & 15) * 4 + g;
      int nt = cl >> 4, n = cl & 15;
      int ks = k >> 5, kr = k & 31, lh = kr >> 3, q = (kr >> 1) & 3;
      int idx = ((jj * 32 + ks) * 4 + nt) * 256 + (lh * 16 + n) * 4 + q;
      astoreU(A.WBh + idx, (uint)h0 | ((uint)h1 << 16));
      astoreU(A.WBl + idx, (uint)l0 | ((uint)l1 << 16));
    }
    if (i0 < 512 * Bn) {
      int hid = i0 >> 7, b = i0 & 127;
      astoreU(A.dh1pk + ((size_t)((hid >> 3) * 128 + b)) * 8 + (hid & 7),
              packsplit(aloadF(A.sdT + (size_t)hid * Bn + b)));
      astoreU(A.dh2pk + ((size_t)((hid >> 3) * 128 + b)) * 8 + (hid & 7),
              packsplit(aloadF(A.sdT + (size_t)(1024 + hid) * Bn + b)));
    }
  }
  gbar();

  // ---- main loop ----
  MC c;
  c.WAh = A.WAh; c.WAl = A.WAl; c.WBh = A.WBh; c.WBl = A.WBl;
  c.dh1pk = A.dh1pk; c.dh2pk = A.dh2pk;
  c.h1pk = A.h1pk; c.h2pk = A.h2pk;
  c.beffP = A.beffP; c.db2P = A.db2P; c.Wp = A.Wp; c.bp = A.bp; c.out = A.out;
  c.accI = A.accI + pod * 3072;
  c.NTu = (uint*)buf;            // 3072 uints ([kt 24][16][8])
  c.plog = buf + 3072;           // 64 slots x 4 r x 68 = 17408
  c.gbuf = buf + 20480;          // 1024
  c.cst  = buf + 21504;          // 1024
  c.h2s  = buf + 22528;          // 256
  c.j = bid & 31;
  c.b0 = pod * 16;
  if (tid < 256) {
    int h = tid >> 4, bl = tid & 15;
    c.cst[512 + tid] = aloadF(A.sdT + (size_t)(512 + c.j * 16 + h) * Bn + c.b0 + bl);
    c.cst[768 + tid] = aloadF(A.sdT + (size_t)(1536 + c.j * 16 + h) * Bn + c.b0 + bl);
  }
  {
    int cl = tid >> 4, bl = tid & 15;
    beffL[tid] = aloadF(A.beffP + (size_t)(c.j * 64 + cl) * Bn + c.b0 + bl);
    db2L[tid] = A.db2P[c.j * 64 + cl];
  }
  for (int i = tid; i < 3072; i += NTHR) c.NTu[i] = 0u;   // note(0) = 0 + pad rows
  __syncthreads();

  for (int t = 0; t < TTn; t++)
    stepFn(c, t, beffL, db2L, pod, tgt);
  smTail(c, TTn);
}

extern "C" void kernel_launch(void* const* d_in, const int* in_sizes, int n_in,
                              void* d_out, int out_size, void* d_ws, size_t ws_size,
                              hipStream_t stream) {
  (void)in_sizes; (void)n_in; (void)out_size; (void)ws_size;
  KA a;
  a.z   = (const float*)d_in[0];
  a.Wz  = (const float*)d_in[3];  a.bz  = (const float*)d_in[4];
  // d_in[5] = cond_W1 unused (conductor input x0 == 0)
  a.cU1 = (const float*)d_in[6];  a.cb1 = (const float*)d_in[7];
  a.cW2 = (const float*)d_in[8];  a.cU2 = (const float*)d_in[9];  a.cb2 = (const float*)d_in[10];
  a.Wcd = (const float*)d_in[11]; a.bcd = (const float*)d_in[12];
  a.dW1 = (const float*)d_in[13]; a.dU1 = (const float*)d_in[14]; a.db1 = (const float*)d_in[15];
  a.dW2 = (const float*)d_in[16]; a.dU2 = (const float*)d_in[17]; a.db2 = (const float*)d_in[18];
  a.Wp  = (const float*)d_in[19]; a.bp  = (const float*)d_in[20];

  float* ws = (float*)d_ws;
  size_t off = 0;
  a.zT    = ws + off; off += (size_t)512  * Bn;
  a.sT    = ws + off; off += (size_t)NGn  * Bn;
  a.ggate = ws + off; off += (size_t)NGn  * Bn;
  a.h1cT  = ws + off; off += (size_t)512  * Bn;
  a.ceT   = ws + off; off += (size_t)512  * Bn;
  a.sdT   = ws + off; off += (size_t)NGn  * Bn;       // dh1|dc1|dh2|dc2
  a.beffP = ws + off; off += (size_t)NGn  * Bn;       // [cp][b]
  a.db1P  = ws + off; off += (size_t)NGn;
  a.db2P  = ws + off; off += (size_t)NGn;
  a.WEp   = ws + off; off += (size_t)512 * NGn;       // aliased by WBh in P4
  a.WBh   = (uint*)a.WEp;
  a.WBl   = (uint*)(ws + off); off += (size_t)1048576;
  a.WAh   = (uint*)(ws + off); off += (size_t)720896;
  a.WAl   = (uint*)(ws + off); off += (size_t)720896;
  a.h1pk  = (uint*)(ws + off); off += (size_t)2 * HPAR;
  a.h2pk  = (uint*)(ws + off); off += (size_t)2 * HPAR;
  a.dh1pk = (uint*)(ws + off); off += (size_t)HPAR;
  a.dh2pk = (uint*)(ws + off); off += (size_t)HPAR;
  a.accI  = (int*)(ws + off);  off += (size_t)2 * ACC_PAR;
  a.out   = (float*)d_out;

  hd_kernel<<<dim3(NBLK), dim3(NTHR), 0, stream>>>(a);
}